// Round 14
// baseline (1024.009 us; speedup 1.0000x reference)
//
#include <hip/hip_runtime.h>
#include <hip/hip_bf16.h>

constexpr int kN    = 100000;
constexpr int kE    = 1600000;
constexpr int kD    = 64;
constexpr int kNF   = 9;
constexpr int kCARD = 16;
constexpr int kBF   = 16;
constexpr int kScanBlocks = (kN + 1023) / 1024;  // 98
constexpr int kNB   = (kN + 127) / 128;          // 782 node blocks

// histogram privatization geometry
constexpr int kHC    = 8;             // node chunks
constexpr int kHS    = 64;            // edge slices
constexpr int kChunk = kN / kHC;      // 12500 nodes per chunk
constexpr int kSlice = kE / kHS;      // 25000 edges per slice

typedef __bf16 bf16x8 __attribute__((ext_vector_type(8)));
typedef float f32x4 __attribute__((ext_vector_type(4)));
typedef float f32x2 __attribute__((ext_vector_type(2)));
union U4BF { uint4 u; bf16x8 v; };

__device__ __forceinline__ float sigm(float v) { return 1.f / (1.f + __expf(-v)); }
__device__ __forceinline__ float tanh_f(float v) { return 1.f - 2.f / (__expf(2.f * v) + 1.f); }

__device__ __forceinline__ unsigned bf16_bits(float v) {
  unsigned u = __float_as_uint(v);
  return (u + 0x7fffu + ((u >> 16) & 1u)) >> 16;
}

// ---------- privatized degree histogram: block (c,s) counts chunk c over slice s ----
__global__ __launch_bounds__(256) void k_hist(const int* __restrict__ row,
                                              const int* __restrict__ col,
                                              unsigned short* __restrict__ part) {
  __shared__ unsigned bins[kChunk];  // 50 KB
  int tid = threadIdx.x;
  int c = blockIdx.x / kHS, s = blockIdx.x % kHS;
  int nlo = c * kChunk;
  for (int i = tid; i < kChunk; i += 256) bins[i] = 0u;
  __syncthreads();
  int e0 = s * kSlice;
  for (int i = tid; i < kSlice; i += 256) {
    int r = row[e0 + i];
    int cc = col[e0 + i];
    unsigned ur = (unsigned)(r - nlo);
    unsigned uc = (unsigned)(cc - nlo);
    if (ur < (unsigned)kChunk) atomicAdd(&bins[ur], 1u);
    if (uc < (unsigned)kChunk) atomicAdd(&bins[uc], 0x10000u);
  }
  __syncthreads();
  unsigned short* dst = part + (size_t)blockIdx.x * kChunk;
  for (int i = tid; i < kChunk; i += 256) {
    unsigned v = bins[i];
    dst[i] = (unsigned short)((v & 0xffu) | ((v >> 8) & 0xff00u));
  }
}

// ---------- merge partials; rewrite part in place with exclusive col prefix ----------
__global__ void k_hmerge(unsigned short* __restrict__ part,
                         float* __restrict__ degf, float* __restrict__ dinv,
                         int* __restrict__ cntc) {
  int n = blockIdx.x * 256 + threadIdx.x;
  if (n >= kN) return;
  int c = n / kChunk, j = n % kChunk;
  unsigned short* p = part + (size_t)c * kHS * kChunk + j;
  unsigned sr = 0, run = 0;
#pragma unroll
  for (int s = 0; s < kHS; s++) {
    unsigned v = p[(size_t)s * kChunk];
    p[(size_t)s * kChunk] = (unsigned short)run;  // exclusive col prefix
    run += v >> 8;
    sr += v & 0xffu;
  }
  float d = (float)sr + 1.f;
  degf[n] = d;
  dinv[n] = rsqrtf(d);
  cntc[n] = (int)run;
}

// ---------- multi-block exclusive scan of col counts ----------
__global__ __launch_bounds__(1024) void k_scanA(const int* __restrict__ cnt,
                                                int* __restrict__ loc,
                                                int* __restrict__ bsum) {
  __shared__ int part[1024];
  int tid = threadIdx.x;
  int i = blockIdx.x * 1024 + tid;
  int v = (i < kN) ? cnt[i] : 0;
  part[tid] = v;
  __syncthreads();
  for (int off = 1; off < 1024; off <<= 1) {
    int t = (tid >= off) ? part[tid - off] : 0;
    __syncthreads();
    part[tid] += t;
    __syncthreads();
  }
  if (i < kN) loc[i] = part[tid] - v;  // local exclusive
  if (tid == 1023) bsum[blockIdx.x] = part[1023];
}

__global__ __launch_bounds__(128) void k_scanB(const int* __restrict__ bsum,
                                               int* __restrict__ boff) {
  __shared__ int p[128];
  int tid = threadIdx.x;
  int v = (tid < kScanBlocks) ? bsum[tid] : 0;
  p[tid] = v;
  __syncthreads();
  for (int off = 1; off < 128; off <<= 1) {
    int t = (tid >= off) ? p[tid - off] : 0;
    __syncthreads();
    p[tid] += t;
    __syncthreads();
  }
  boff[tid] = p[tid] - v;  // exclusive
}

__global__ __launch_bounds__(1024) void k_scanC(const int* __restrict__ loc,
                                                const int* __restrict__ boff,
                                                int* __restrict__ ptr) {
  int i = blockIdx.x * 1024 + threadIdx.x;
  if (i < kN) ptr[i] = loc[i] + boff[blockIdx.x];
  if (i == 0) ptr[kN] = kE;  // grand total is statically kE
}

// ---------- scatter via LDS offsets (zero global atomics) ----------
// re.x stores the PRE-SCALED xb byte offset (r << 7); re.y the edge id.
__global__ __launch_bounds__(256) void k_scatter2(
    const int* __restrict__ row, const int* __restrict__ col,
    const float* __restrict__ dinv, const int* __restrict__ ptr,
    const unsigned short* __restrict__ part,
    int2* __restrict__ re, float* __restrict__ nrm) {
  __shared__ unsigned bins[kChunk];  // 50 KB
  int tid = threadIdx.x;
  int c = blockIdx.x / kHS, s = blockIdx.x % kHS;
  int nlo = c * kChunk;
  const unsigned short* pp = part + (size_t)blockIdx.x * kChunk;
  for (int i = tid; i < kChunk; i += 256)
    bins[i] = (unsigned)ptr[nlo + i] + (unsigned)pp[i];
  __syncthreads();
  int e0 = s * kSlice;
  for (int i = tid; i < kSlice; i += 256) {
    int e = e0 + i;
    int cc = col[e];
    unsigned uc = (unsigned)(cc - nlo);
    if (uc < (unsigned)kChunk) {
      int r = row[e];
      int p = (int)atomicAdd(&bins[uc], 1u);
      re[p] = make_int2(r << 7, e);
      nrm[p] = dinv[r] * dinv[cc];
    }
  }
}

// ---------- reorder edge_attr into CSR order as bf16 (gathered reads, coalesced writes)
__global__ void k_gea(const int2* __restrict__ re, const float* __restrict__ ea,
                      unsigned short* __restrict__ ea_s) {
  int idx = blockIdx.x * 256 + threadIdx.x;
  int p = idx >> 2, c = idx & 3;
  if (p < kE) {
    int e = re[p].y;
    float4 v = *(const float4*)(ea + (size_t)e * 16 + c * 4);
    ushort4 o;
    o.x = (unsigned short)bf16_bits(v.x);
    o.y = (unsigned short)bf16_bits(v.y);
    o.z = (unsigned short)bf16_bits(v.z);
    o.w = (unsigned short)bf16_bits(v.w);
    *(ushort4*)(ea_s + (size_t)p * 16 + c * 4) = o;
  }
}

// ---------- edge_attr moments: sumA[16], M = A^T A [16x16] ----------
__global__ __launch_bounds__(256) void k_stats(const float* __restrict__ ea,
                                               float* __restrict__ sumA,
                                               float* __restrict__ Msum) {
  __shared__ float tile[1024];
  int tid = threadIdx.x;
  int i = tid >> 4, j = tid & 15;
  float accM = 0.f, accS = 0.f;
  const int T = kE / 64;
  for (int t = blockIdx.x; t < T; t += gridDim.x) {
    const float4* src = (const float4*)(ea + (size_t)t * 1024);
    ((float4*)tile)[tid] = src[tid];
    __syncthreads();
#pragma unroll 8
    for (int e = 0; e < 64; e++) {
      float aj = tile[e * 16 + j];
      accM += tile[e * 16 + i] * aj;
      if (i == 0) accS += aj;
    }
    __syncthreads();
  }
  atomicAdd(&Msum[i * 16 + j], accM);
  if (i == 0) atomicAdd(&sumA[j], accS);
}

// ---------- fold bond-linear + BN into WeffbT (bf16, [l][d][k]) + beff ----------
__global__ __launch_bounds__(256) void k_bnfold(
    const float* __restrict__ sumA, const float* __restrict__ Msum,
    const float* __restrict__ bond_W, const float* __restrict__ bond_b,
    const float* __restrict__ bond_g, const float* __restrict__ bond_beta,
    unsigned short* __restrict__ WeffbT, float* __restrict__ beff) {
  __shared__ float Ms[256];
  __shared__ float ab[16];
  int tid = threadIdx.x;
  Ms[tid] = Msum[tid] * (1.f / (float)kE);
  if (tid < 16) ab[tid] = sumA[tid] * (1.f / (float)kE);
  __syncthreads();
  if (tid < 192) {
    int l = tid / 64, d = tid % 64;
    const float* W = bond_W + l * kBF * kD;
    float w[16];
#pragma unroll
    for (int k = 0; k < 16; k++) w[k] = W[k * 64 + d];
    float b = bond_b[l * 64 + d];
    float lin = 0.f;
#pragma unroll
    for (int k = 0; k < 16; k++) lin += ab[k] * w[k];
    float mu = lin + b;
    float q = 0.f;
#pragma unroll
    for (int i = 0; i < 16; i++) {
      float wi = w[i];
#pragma unroll
      for (int k = 0; k < 16; k++) q += Ms[i * 16 + k] * wi * w[k];
    }
    float ex2 = q + 2.f * b * lin + b * b;
    float var = ex2 - mu * mu;
    float s = bond_g[l * 64 + d] * rsqrtf(var + 1e-6f);
#pragma unroll
    for (int k = 0; k < 16; k++)
      WeffbT[(size_t)(l * 64 + d) * 16 + k] = (unsigned short)bf16_bits(w[k] * s);
    beff[l * 64 + d] = (b - mu) * s + bond_beta[l * 64 + d];
  }
}

// ---------- GRU weight prep: Bt[l][j][k] bf16, j in [0,256), k in [0,128) ----------
// x half of A (k>=64) in PERMUTED dim order: pos -> dim (pos&3)*16 + (pos>>2).
__global__ void k_wprep(const float* __restrict__ Wih, const float* __restrict__ Whh,
                        unsigned short* __restrict__ Bt) {
  int idx = blockIdx.x * 256 + threadIdx.x;
  if (idx >= 3 * 256 * 128) return;
  int l = idx / (256 * 128);
  int rem = idx % (256 * 128);
  int j = rem / 128, k = rem % 128;
  const float* ih = Wih + l * 192 * 64;
  const float* hh = Whh + l * 192 * 64;
  float v;
  if (k < 64) {
    if (j < 192) v = ih[j * 64 + k];
    else         v = 0.f;
  } else {
    int pos = k - 64;
    int kd = (pos & 3) * 16 + (pos >> 2);  // permuted x dim
    if (j < 128)      v = hh[j * 64 + kd];
    else if (j < 192) v = 0.f;
    else              v = hh[(j - 64) * 64 + kd];
  }
  Bt[idx] = (unsigned short)bf16_bits(v);
}

// ---------- fold proj + layer-0 linear -> WeffTb (bf16, [out 64][in 128]) + beff2 ----
__global__ __launch_bounds__(256) void k_wfold(
    const float* __restrict__ projW, const float* __restrict__ projb,
    const float* __restrict__ W1, const float* __restrict__ b1,
    unsigned short* __restrict__ WeffTb, float* __restrict__ beff2) {
  __shared__ float W2[64 * 64];  // 16 KB
  int tid = threadIdx.x;
  for (int i = tid; i < 64 * 64 / 4; i += 256)
    ((float4*)W2)[i] = ((const float4*)W1)[i];
  __syncthreads();
  int ccol = tid & 63, rg = tid >> 6;
#pragma unroll
  for (int i = 0; i < 4; i++) {
    int r = blockIdx.x * 16 + rg + i * 4;
    float s = 0.f;
#pragma unroll 8
    for (int k = 0; k < 64; k++) s += projW[r * 64 + k] * W2[k * 64 + ccol];
    WeffTb[ccol * 128 + r] = (unsigned short)bf16_bits(s);
  }
  if (blockIdx.x == 0 && tid < 64) {
    float s = b1[tid];
    for (int k = 0; k < 64; k++) s += projb[k] * W2[k * 64 + tid];
    beff2[tid] = s;
  }
}

// ---------- lin_W transpose -> bf16 [l][out 64][in 64] for MFMA B frags ----------
__global__ void k_wlin(const float* __restrict__ lin_W,
                       unsigned short* __restrict__ linWb) {
  int idx = blockIdx.x * 256 + threadIdx.x;
  if (idx >= 3 * 64 * 64) return;
  int l = idx / 4096, rem = idx % 4096;
  int o = rem / 64, i = rem % 64;
  linWb[idx] = (unsigned short)bf16_bits(lin_W[l * 4096 + i * 64 + o]);
}

// ---------- MFMA encoder: xb = bf16([atom_x | sum_f emb] @ Weff + beff2) ----------
// fp32 x array deleted: downstream (k_aggr A-frags, k_gru blend) reads xb only.
__global__ __launch_bounds__(256) void k_enc3(
    const float* __restrict__ atom_x, const int* __restrict__ feat,
    const float* __restrict__ emb, const unsigned short* __restrict__ WTb,
    const float* __restrict__ beff2, unsigned short* __restrict__ xb) {
  __shared__ unsigned short A[128 * 128];  // 32 KB
  int tid = threadIdx.x;
  int lane = tid & 63, wv = tid >> 6;
  int nbase = blockIdx.x * 128;
  for (int it = 0; it < 32; it++) {
    int nl = it * 4 + wv;
    int nc = min(nbase + nl, kN - 1);
    float ax = atom_x[(size_t)nc * 64 + lane];
    const int* fr = feat + (size_t)nc * kNF;
    float s = 0.f;
#pragma unroll
    for (int f = 0; f < kNF; f++) s += emb[(f * kCARD + fr[f]) * 64 + lane];
    int swz = (nl & 7) << 3;
    A[(nl * 128 + lane) ^ swz] = (unsigned short)bf16_bits(ax);
    A[(nl * 128 + 64 + lane) ^ swz] = (unsigned short)bf16_bits(s);
  }
  __syncthreads();
  int c = lane & 15, q = lane >> 4;
  int d = wv * 16 + c;
  bf16x8 bfr[4];
#pragma unroll
  for (int kk = 0; kk < 4; kk++) {
    U4BF t;
    t.u = *(const uint4*)(WTb + (size_t)d * 128 + kk * 32 + q * 8);
    bfr[kk] = t.v;
  }
  float bd = beff2[d];
  int perm = c * 4 + wv;  // (d&15)*4 + (d>>4)
  int rswz = (c & 7) << 3;
#pragma unroll 2
  for (int mt = 0; mt < 8; mt++) {
    bf16x8 afr[4];
#pragma unroll
    for (int kk = 0; kk < 4; kk++) {
      U4BF t;
      t.u = *(const uint4*)(A + (((mt * 16 + c) * 128 + kk * 32 + q * 8) ^ rswz));
      afr[kk] = t.v;
    }
    f32x4 a = {bd, bd, bd, bd};
#pragma unroll
    for (int kk = 0; kk < 4; kk++)
      a = __builtin_amdgcn_mfma_f32_16x16x32_bf16(afr[kk], bfr[kk], a, 0, 0, 0);
#pragma unroll
    for (int reg = 0; reg < 4; reg++) {
      int n = nbase + mt * 16 + q * 4 + reg;
      if (n < kN)
        xb[(size_t)n * 64 + perm] = (unsigned short)bf16_bits(a[reg]);
    }
  }
}

// ---------- MFMA lin (layers 1,2): xb = bf16(relu(BN(h)) @ lin_W + lin_b) ----------
__global__ __launch_bounds__(256) void k_lin3(
    const float* __restrict__ hin, const unsigned short* __restrict__ Wb,
    const float* __restrict__ bg,
    const float* __restrict__ bnsum, const float* __restrict__ bnss,
    const float* __restrict__ bng, const float* __restrict__ bnb,
    unsigned short* __restrict__ xb) {
  __shared__ unsigned short A[128 * 64];  // 16 KB
  int tid = threadIdx.x;
  int lane = tid & 63, wv = tid >> 6;
  int nbase = blockIdx.x * 128;
  float m = bnsum[lane] * (1.f / (float)kN);
  float var = bnss[lane] * (1.f / (float)kN) - m * m;
  float sc = rsqrtf(var + 1e-5f) * bng[lane];
  float bb = bnb[lane];
  for (int it = 0; it < 32; it++) {
    int nl = it * 4 + wv;
    int nc = min(nbase + nl, kN - 1);
    float v = hin[(size_t)nc * 64 + lane];
    v = fmaxf((v - m) * sc + bb, 0.f);
    A[(nl * 64 + lane) ^ ((nl & 7) << 3)] = (unsigned short)bf16_bits(v);
  }
  __syncthreads();
  int c = lane & 15, q = lane >> 4;
  int d = wv * 16 + c;
  bf16x8 bfr[2];
#pragma unroll
  for (int kk = 0; kk < 2; kk++) {
    U4BF t;
    t.u = *(const uint4*)(Wb + (size_t)d * 64 + kk * 32 + q * 8);
    bfr[kk] = t.v;
  }
  float bd = bg[d];
  int perm = c * 4 + wv;
  int rswz = (c & 7) << 3;
#pragma unroll 2
  for (int mt = 0; mt < 8; mt++) {
    bf16x8 afr[2];
#pragma unroll
    for (int kk = 0; kk < 2; kk++) {
      U4BF t;
      t.u = *(const uint4*)(A + (((mt * 16 + c) * 64 + kk * 32 + q * 8) ^ rswz));
      afr[kk] = t.v;
    }
    f32x4 a = {bd, bd, bd, bd};
#pragma unroll
    for (int kk = 0; kk < 2; kk++)
      a = __builtin_amdgcn_mfma_f32_16x16x32_bf16(afr[kk], bfr[kk], a, 0, 0, 0);
#pragma unroll
    for (int reg = 0; reg < 4; reg++) {
      int n = nbase + mt * 16 + q * 4 + reg;
      if (n < kN)
        xb[(size_t)n * 64 + perm] = (unsigned short)bf16_bits(a[reg]);
    }
  }
}

// ---------- CSR gather with MFMA bond: 4 nodes per wave, prologue prefetch ----------
__global__ __launch_bounds__(256) void k_aggr(
    const int* __restrict__ ptr, const int2* __restrict__ re,
    const float* __restrict__ nrm, const unsigned short* __restrict__ ea_s,
    const unsigned short* __restrict__ xb, const unsigned short* __restrict__ WeffbT,
    const float* __restrict__ beff, unsigned short* __restrict__ aggr_b) {
  int lane = threadIdx.x & 63, wv = threadIdx.x >> 6;
  int nb = blockIdx.x * 16 + wv * 4;  // first of 4 nodes for this wave
  if (nb >= kN) return;
  int c = lane & 15, q = lane >> 4;

  U4BF z; z.u = make_uint4(0u, 0u, 0u, 0u);
  bf16x8 bfr[4];
#pragma unroll
  for (int nt = 0; nt < 4; nt++) {
    if (q < 2) {
      U4BF t;
      t.u = *(const uint4*)(WeffbT + (size_t)(nt * 16 + c) * 16 + q * 8);
      bfr[nt] = t.v;
    } else {
      bfr[nt] = z.v;
    }
  }
  float be4[4];
#pragma unroll
  for (int nt = 0; nt < 4; nt++) be4[nt] = beff[nt * 16 + c];
  const char* xcol = (const char*)xb + (c << 3);  // lane's 8B slice base
  const f32x2 zero2 = {0.f, 0.f};

  // prologue: ranges (uniform/scalar) + first-window re/nrm for all 4 nodes
  int st[4], en[4];
#pragma unroll
  for (int i = 0; i < 4; i++) {
    bool ok = (nb + i) < kN;
    st[i] = ok ? ptr[nb + i] : 0;
    en[i] = ok ? ptr[nb + i + 1] : 0;
  }
  int2 m0[4];
  float nr0[4];
#pragma unroll
  for (int i = 0; i < 4; i++) {
    int j = st[i] + lane;
    bool val = j < en[i];
    m0[i] = val ? re[j] : make_int2(0, 0);
    nr0[i] = val ? nrm[j] : 0.f;
  }

  for (int i = 0; i < 4; i++) {
    int n = nb + i;
    if (n >= kN) break;
    int start = st[i], end = en[i];
    f32x2 p01 = zero2, p23 = zero2;  // dims {c,16+c} and {32+c,48+c} partials
    int2 m = m0[i];
    float nr = nr0[i];

    for (int j0 = start; j0 < end; j0 += 64) {
      if (j0 != start) {  // windows >=1 (rare at avg degree 16)
        int j = j0 + lane;
        bool val = j < end;
        m = val ? re[j] : make_int2(0, 0);
        nr = val ? nrm[j] : 0.f;
      }
      int cnt = min(64, end - j0);
      int mts = (cnt + 15) >> 4;
      for (int mt = 0; mt < mts; mt++) {
        bf16x8 afr;
        if (q < 2) {
          U4BF t;
          t.u = *(const uint4*)(ea_s + (size_t)(j0 + mt * 16 + c) * 16 + q * 8);
          afr = t.v;
        } else {
          afr = z.v;
        }
        f32x4 bond[4];
#pragma unroll
        for (int nt = 0; nt < 4; nt++) {
          f32x4 a = {be4[nt], be4[nt], be4[nt], be4[nt]};
          bond[nt] = __builtin_amdgcn_mfma_f32_16x16x32_bf16(afr, bfr[nt], a, 0, 0, 0);
        }
#pragma unroll
        for (int reg = 0; reg < 4; reg++) {
          int el = mt * 16 + (q << 2) + reg;
          int rt = __builtin_amdgcn_ds_bpermute(el << 2, m.x);  // byte offset
          float nv = __uint_as_float(
              (unsigned)__builtin_amdgcn_ds_bpermute(el << 2, (int)__float_as_uint(nr)));
          uint2 xw = *(const uint2*)(xcol + rt);
          f32x2 xva = {__uint_as_float(xw.x << 16),
                       __uint_as_float(xw.x & 0xffff0000u)};
          f32x2 xvb = {__uint_as_float(xw.y << 16),
                       __uint_as_float(xw.y & 0xffff0000u)};
          f32x2 ba = {bond[0][reg], bond[1][reg]};
          f32x2 bb = {bond[2][reg], bond[3][reg]};
          f32x2 ta = __builtin_elementwise_max(xva + ba, zero2);
          f32x2 tb = __builtin_elementwise_max(xvb + bb, zero2);
          f32x2 nv2 = {nv, nv};
          p01 += nv2 * ta;
          p23 += nv2 * tb;
        }
      }
    }
    // reduce partials across quads (lanes c, c+16, c+32, c+48 share dims)
    float pa0 = p01.x, pa1 = p01.y, pa2 = p23.x, pa3 = p23.y;
    pa0 += __shfl_xor(pa0, 16, 64); pa0 += __shfl_xor(pa0, 32, 64);
    pa1 += __shfl_xor(pa1, 16, 64); pa1 += __shfl_xor(pa1, 32, 64);
    pa2 += __shfl_xor(pa2, 16, 64); pa2 += __shfl_xor(pa2, 32, 64);
    pa3 += __shfl_xor(pa3, 16, 64); pa3 += __shfl_xor(pa3, 32, 64);
    float outv = (q == 0) ? pa0 : (q == 1) ? pa1 : (q == 2) ? pa2 : pa3;
    aggr_b[(size_t)n * 64 + lane] = (unsigned short)bf16_bits(outv);
  }
}

// ---------- MFMA GRU: x read from xb (bf16, permuted slot c*4+w) — fp32 x deleted --
__global__ __launch_bounds__(256) void k_gru_mfma(
    const unsigned short* __restrict__ aggr_b, const unsigned short* __restrict__ xb,
    const unsigned short* __restrict__ Bt,
    const float* __restrict__ bih, const float* __restrict__ bhh,
    const float* __restrict__ root, const float* __restrict__ degf,
    float* __restrict__ h, float* __restrict__ bnsum, float* __restrict__ bnss) {
  int tid = threadIdx.x;
  int w = tid >> 6;
  int lane = tid & 63;
  int c = lane & 15, q = lane >> 4;
  int nbase = blockIdx.x * 128;
  int d = w * 16 + c;
  int perm = c * 4 + w;  // xb slot for dim d

  bf16x8 bfr[4][4];
#pragma unroll
  for (int g = 0; g < 4; g++)
#pragma unroll
    for (int kk = 0; kk < 4; kk++) {
      U4BF t;
      t.u = *(const uint4*)(Bt + (size_t)((g * 4 + w) * 16 + c) * 128 + kk * 32 + q * 8);
      bfr[g][kk] = t.v;
    }

  float br = bih[d] + bhh[d];
  float bz = bih[64 + d] + bhh[64 + d];
  float bin = bih[128 + d];
  float bhn = bhh[128 + d];
  float rt = root[d];
  float s1 = 0.f, s2 = 0.f;

#pragma unroll 2
  for (int mt = 0; mt < 8; mt++) {
    int na = nbase + mt * 16 + c;
    int nac = min(na, kN - 1);
    bf16x8 afr[4];
#pragma unroll
    for (int kk = 0; kk < 4; kk++) {
      const unsigned short* src = (kk < 2)
          ? aggr_b + (size_t)nac * 64 + kk * 32 + q * 8
          : xb + (size_t)nac * 64 + (kk - 2) * 32 + q * 8;
      U4BF t;
      t.u = *(const uint4*)src;
      afr[kk] = t.v;
    }
    f32x4 acc[4];
#pragma unroll
    for (int g = 0; g < 4; g++) {
      f32x4 a = {0.f, 0.f, 0.f, 0.f};
#pragma unroll
      for (int kk = 0; kk < 4; kk++)
        a = __builtin_amdgcn_mfma_f32_16x16x32_bf16(afr[kk], bfr[g][kk], a, 0, 0, 0);
      acc[g] = a;
    }
#pragma unroll
    for (int reg = 0; reg < 4; reg++) {
      int n = nbase + mt * 16 + q * 4 + reg;
      if (n < kN) {
        float xv = __uint_as_float(
            ((unsigned)xb[(size_t)n * 64 + perm]) << 16);
        float r = sigm(acc[0][reg] + br);
        float zz = sigm(acc[1][reg] + bz);
        float nn = tanh_f(acc[2][reg] + bin + r * (acc[3][reg] + bhn));
        float upd = (1.f - zz) * nn + zz * xv;
        float hl = upd + fmaxf(xv + rt, 0.f) / degf[n];
        h[(size_t)n * 64 + d] = hl;
        s1 += hl;
        s2 += hl * hl;
      }
    }
  }
  s1 += __shfl_xor(s1, 16, 64);
  s1 += __shfl_xor(s1, 32, 64);
  s2 += __shfl_xor(s2, 16, 64);
  s2 += __shfl_xor(s2, 32, 64);
  if (q == 0) {
    atomicAdd(&bnsum[d], s1);
    atomicAdd(&bnss[d], s2);
  }
}

// ---------- final BN (layer 2, no relu) -> d_out ----------
__global__ void k_final(const float* __restrict__ h, const float* __restrict__ bnsum,
                        const float* __restrict__ bnss, const float* __restrict__ bng,
                        const float* __restrict__ bnb, float* __restrict__ out) {
  int idx = blockIdx.x * blockDim.x + threadIdx.x;
  if (idx < kN * kD) {
    int d = idx & 63;
    float m = bnsum[d] * (1.f / (float)kN);
    float var = bnss[d] * (1.f / (float)kN) - m * m;
    float sc = rsqrtf(var + 1e-5f) * bng[d];
    out[idx] = (h[idx] - m) * sc + bnb[d];
  }
}

extern "C" void kernel_launch(void* const* d_in, const int* in_sizes, int n_in,
                              void* d_out, int out_size, void* d_ws, size_t ws_size,
                              hipStream_t stream) {
  const float* atom_x       = (const float*)d_in[0];
  const int*   atom_feature = (const int*)d_in[1];
  const int*   edge_index   = (const int*)d_in[2];
  const float* edge_attr    = (const float*)d_in[3];
  const float* atom_emb     = (const float*)d_in[4];
  const float* proj_W       = (const float*)d_in[5];
  const float* proj_b       = (const float*)d_in[6];
  const float* lin_W        = (const float*)d_in[7];
  const float* lin_b        = (const float*)d_in[8];
  const float* root_emb     = (const float*)d_in[9];
  const float* bond_W       = (const float*)d_in[10];
  const float* bond_b       = (const float*)d_in[11];
  const float* bond_g       = (const float*)d_in[12];
  const float* bond_beta    = (const float*)d_in[13];
  const float* gru_Wih      = (const float*)d_in[14];
  const float* gru_bih      = (const float*)d_in[15];
  const float* gru_Whh      = (const float*)d_in[16];
  const float* gru_bhh      = (const float*)d_in[17];
  const float* bn_g         = (const float*)d_in[18];
  const float* bn_b         = (const float*)d_in[19];
  float* out = (float*)d_out;

  const int* row = edge_index;
  const int* col = edge_index + kE;

  float* ws = (float*)d_ws;
  const size_t NH = (size_t)kN * kD;
  float* h     = ws;                         // NH
  float* x     = h + NH;                     // NH (scratch: histogram partials only)
  float* degf  = x + NH;                     // kN
  float* dinv  = degf + kN;                  // kN
  int*   cntr  = (int*)(dinv + kN);          // kN (reused: folded weights)
  int*   cntc  = cntr + kN;                  // kN
  int*   ptr   = cntc + kN;                  // kN+1 (reserve kN+4)
  int*   fill  = ptr + kN + 4;               // kN (unused, layout keep)
  int*   loc   = fill + kN;                  // kN
  int*   bsum  = loc + kN;                   // 128
  int*   boff  = bsum + 128;                 // 128
  int2*  re    = (int2*)(boff + 128);        // kE int2
  float* nrm   = (float*)(re + kE);          // kE
  unsigned short* ea_s   = (unsigned short*)(nrm + kE);      // kE*16 + 1024 pad
  unsigned short* xb     = ea_s + (size_t)kE * 16 + 1024;    // N*64
  unsigned short* aggr_b = xb + (size_t)kN * 64;             // N*64
  unsigned short* Bt     = aggr_b + (size_t)kN * 64;         // 3*256*128
  unsigned short* WeffbT = Bt + 3 * 256 * 128;               // 3*64*16
  float* sumA  = (float*)(WeffbT + 3 * 64 * 16);  // 16
  float* Msum  = sumA + 16;                  // 256
  float* beff  = Msum + 256;                 // 192
  float* bnsum = beff + 192;                 // 64
  float* bnss  = bnsum + 64;                 // 64

  // folded weights live in the (otherwise unused) cntr region
  unsigned short* WeffTb = (unsigned short*)cntr;          // 64*128 u16
  float* beff2 = (float*)(WeffTb + 64 * 128);              // 64 floats
  unsigned short* linWb  = (unsigned short*)(beff2 + 64);  // 3*64*64 u16

  // histogram partials live in the x region (12.8 MB; x fp32 array is no
  // longer materialized — xb bf16 is the only node-feature buffer)
  unsigned short* part = (unsigned short*)x;

  k_wfold<<<8, 256, 0, stream>>>(proj_W, proj_b, lin_W, lin_b, WeffTb, beff2);
  k_wlin<<<(3 * 64 * 64 + 255) / 256, 256, 0, stream>>>(lin_W, linWb);
  k_hist<<<kHC * kHS, 256, 0, stream>>>(row, col, part);
  k_hmerge<<<(kN + 255) / 256, 256, 0, stream>>>(part, degf, dinv, cntc);
  k_scanA<<<kScanBlocks, 1024, 0, stream>>>(cntc, loc, bsum);
  k_scanB<<<1, 128, 0, stream>>>(bsum, boff);
  k_scanC<<<kScanBlocks, 1024, 0, stream>>>(loc, boff, ptr);
  k_scatter2<<<kHC * kHS, 256, 0, stream>>>(row, col, dinv, ptr, part, re, nrm);
  k_gea<<<(kE * 4 + 255) / 256, 256, 0, stream>>>(re, edge_attr, ea_s);

  hipMemsetAsync(sumA, 0, (16 + 256) * sizeof(float), stream);
  k_stats<<<512, 256, 0, stream>>>(edge_attr, sumA, Msum);
  k_bnfold<<<1, 256, 0, stream>>>(sumA, Msum, bond_W, bond_b, bond_g, bond_beta,
                                  WeffbT, beff);
  k_wprep<<<(3 * 256 * 128 + 255) / 256, 256, 0, stream>>>(gru_Wih, gru_Whh, Bt);
  k_enc3<<<kNB, 256, 0, stream>>>(atom_x, atom_feature, atom_emb, WeffTb, beff2,
                                  xb);

  for (int l = 0; l < 3; l++) {
    if (l > 0) {
      k_lin3<<<kNB, 256, 0, stream>>>(h, linWb + (size_t)l * 4096, lin_b + l * 64,
                                      bnsum, bnss, bn_g + (l - 1) * 64,
                                      bn_b + (l - 1) * 64, xb);
    }
    k_aggr<<<(kN + 15) / 16, 256, 0, stream>>>(ptr, re, nrm, ea_s, xb,
                                               WeffbT + (size_t)l * 64 * 16,
                                               beff + l * 64, aggr_b);
    hipMemsetAsync(bnsum, 0, 128 * sizeof(float), stream);
    k_gru_mfma<<<(kN + 127) / 128, 256, 0, stream>>>(
        aggr_b, xb, Bt + (size_t)l * 256 * 128, gru_bih + l * 192,
        gru_bhh + l * 192, root_emb + l * 64, degf, h, bnsum, bnss);
  }
  k_final<<<(kN * kD + 255) / 256, 256, 0, stream>>>(h, bnsum, bnss, bn_g + 2 * 64,
                                                     bn_b + 2 * 64, out);
}

// Round 15
// 990.012 us; speedup vs baseline: 1.0343x; 1.0343x over previous
//
#include <hip/hip_runtime.h>
#include <hip/hip_bf16.h>

constexpr int kN    = 100000;
constexpr int kE    = 1600000;
constexpr int kD    = 64;
constexpr int kNF   = 9;
constexpr int kCARD = 16;
constexpr int kBF   = 16;
constexpr int kScanBlocks = (kN + 1023) / 1024;  // 98
constexpr int kNB   = (kN + 127) / 128;          // 782 node blocks

// histogram privatization geometry
constexpr int kHC    = 8;             // node chunks
constexpr int kHS    = 64;            // edge slices
constexpr int kChunk = kN / kHC;      // 12500 nodes per chunk
constexpr int kSlice = kE / kHS;      // 25000 edges per slice

typedef __bf16 bf16x8 __attribute__((ext_vector_type(8)));
typedef float f32x4 __attribute__((ext_vector_type(4)));
typedef float f32x2 __attribute__((ext_vector_type(2)));
union U4BF { uint4 u; bf16x8 v; };

__device__ __forceinline__ float sigm(float v) { return 1.f / (1.f + __expf(-v)); }
__device__ __forceinline__ float tanh_f(float v) { return 1.f - 2.f / (__expf(2.f * v) + 1.f); }

__device__ __forceinline__ unsigned bf16_bits(float v) {
  unsigned u = __float_as_uint(v);
  return (u + 0x7fffu + ((u >> 16) & 1u)) >> 16;
}

// ---------- privatized degree histogram: block (c,s) counts chunk c over slice s ----
__global__ __launch_bounds__(256) void k_hist(const int* __restrict__ row,
                                              const int* __restrict__ col,
                                              unsigned short* __restrict__ part) {
  __shared__ unsigned bins[kChunk];  // 50 KB
  int tid = threadIdx.x;
  int c = blockIdx.x / kHS, s = blockIdx.x % kHS;
  int nlo = c * kChunk;
  for (int i = tid; i < kChunk; i += 256) bins[i] = 0u;
  __syncthreads();
  int e0 = s * kSlice;
  for (int i = tid; i < kSlice; i += 256) {
    int r = row[e0 + i];
    int cc = col[e0 + i];
    unsigned ur = (unsigned)(r - nlo);
    unsigned uc = (unsigned)(cc - nlo);
    if (ur < (unsigned)kChunk) atomicAdd(&bins[ur], 1u);
    if (uc < (unsigned)kChunk) atomicAdd(&bins[uc], 0x10000u);
  }
  __syncthreads();
  unsigned short* dst = part + (size_t)blockIdx.x * kChunk;
  for (int i = tid; i < kChunk; i += 256) {
    unsigned v = bins[i];
    dst[i] = (unsigned short)((v & 0xffu) | ((v >> 8) & 0xff00u));
  }
}

// ---------- merge partials; rewrite part in place with exclusive col prefix ----------
__global__ void k_hmerge(unsigned short* __restrict__ part,
                         float* __restrict__ degf, float* __restrict__ dinv,
                         int* __restrict__ cntc) {
  int n = blockIdx.x * 256 + threadIdx.x;
  if (n >= kN) return;
  int c = n / kChunk, j = n % kChunk;
  unsigned short* p = part + (size_t)c * kHS * kChunk + j;
  unsigned sr = 0, run = 0;
#pragma unroll
  for (int s = 0; s < kHS; s++) {
    unsigned v = p[(size_t)s * kChunk];
    p[(size_t)s * kChunk] = (unsigned short)run;  // exclusive col prefix
    run += v >> 8;
    sr += v & 0xffu;
  }
  float d = (float)sr + 1.f;
  degf[n] = d;
  dinv[n] = rsqrtf(d);
  cntc[n] = (int)run;
}

// ---------- multi-block exclusive scan of col counts ----------
__global__ __launch_bounds__(1024) void k_scanA(const int* __restrict__ cnt,
                                                int* __restrict__ loc,
                                                int* __restrict__ bsum) {
  __shared__ int part[1024];
  int tid = threadIdx.x;
  int i = blockIdx.x * 1024 + tid;
  int v = (i < kN) ? cnt[i] : 0;
  part[tid] = v;
  __syncthreads();
  for (int off = 1; off < 1024; off <<= 1) {
    int t = (tid >= off) ? part[tid - off] : 0;
    __syncthreads();
    part[tid] += t;
    __syncthreads();
  }
  if (i < kN) loc[i] = part[tid] - v;  // local exclusive
  if (tid == 1023) bsum[blockIdx.x] = part[1023];
}

__global__ __launch_bounds__(128) void k_scanB(const int* __restrict__ bsum,
                                               int* __restrict__ boff) {
  __shared__ int p[128];
  int tid = threadIdx.x;
  int v = (tid < kScanBlocks) ? bsum[tid] : 0;
  p[tid] = v;
  __syncthreads();
  for (int off = 1; off < 128; off <<= 1) {
    int t = (tid >= off) ? p[tid - off] : 0;
    __syncthreads();
    p[tid] += t;
    __syncthreads();
  }
  boff[tid] = p[tid] - v;  // exclusive
}

__global__ __launch_bounds__(1024) void k_scanC(const int* __restrict__ loc,
                                                const int* __restrict__ boff,
                                                int* __restrict__ ptr) {
  int i = blockIdx.x * 1024 + threadIdx.x;
  if (i < kN) ptr[i] = loc[i] + boff[blockIdx.x];
  if (i == 0) ptr[kN] = kE;  // grand total is statically kE
}

// ---------- scatter via LDS offsets (zero global atomics) ----------
// re.x stores the PRE-SCALED xb byte offset (r << 7); re.y the edge id.
__global__ __launch_bounds__(256) void k_scatter2(
    const int* __restrict__ row, const int* __restrict__ col,
    const float* __restrict__ dinv, const int* __restrict__ ptr,
    const unsigned short* __restrict__ part,
    int2* __restrict__ re, float* __restrict__ nrm) {
  __shared__ unsigned bins[kChunk];  // 50 KB
  int tid = threadIdx.x;
  int c = blockIdx.x / kHS, s = blockIdx.x % kHS;
  int nlo = c * kChunk;
  const unsigned short* pp = part + (size_t)blockIdx.x * kChunk;
  for (int i = tid; i < kChunk; i += 256)
    bins[i] = (unsigned)ptr[nlo + i] + (unsigned)pp[i];
  __syncthreads();
  int e0 = s * kSlice;
  for (int i = tid; i < kSlice; i += 256) {
    int e = e0 + i;
    int cc = col[e];
    unsigned uc = (unsigned)(cc - nlo);
    if (uc < (unsigned)kChunk) {
      int r = row[e];
      int p = (int)atomicAdd(&bins[uc], 1u);
      re[p] = make_int2(r << 7, e);
      nrm[p] = dinv[r] * dinv[cc];
    }
  }
}

// ---------- reorder edge_attr into CSR order as bf16 (gathered reads, coalesced writes)
__global__ void k_gea(const int2* __restrict__ re, const float* __restrict__ ea,
                      unsigned short* __restrict__ ea_s) {
  int idx = blockIdx.x * 256 + threadIdx.x;
  int p = idx >> 2, c = idx & 3;
  if (p < kE) {
    int e = re[p].y;
    float4 v = *(const float4*)(ea + (size_t)e * 16 + c * 4);
    ushort4 o;
    o.x = (unsigned short)bf16_bits(v.x);
    o.y = (unsigned short)bf16_bits(v.y);
    o.z = (unsigned short)bf16_bits(v.z);
    o.w = (unsigned short)bf16_bits(v.w);
    *(ushort4*)(ea_s + (size_t)p * 16 + c * 4) = o;
  }
}

// ---------- edge_attr moments: sumA[16], M = A^T A [16x16] ----------
__global__ __launch_bounds__(256) void k_stats(const float* __restrict__ ea,
                                               float* __restrict__ sumA,
                                               float* __restrict__ Msum) {
  __shared__ float tile[1024];
  int tid = threadIdx.x;
  int i = tid >> 4, j = tid & 15;
  float accM = 0.f, accS = 0.f;
  const int T = kE / 64;
  for (int t = blockIdx.x; t < T; t += gridDim.x) {
    const float4* src = (const float4*)(ea + (size_t)t * 1024);
    ((float4*)tile)[tid] = src[tid];
    __syncthreads();
#pragma unroll 8
    for (int e = 0; e < 64; e++) {
      float aj = tile[e * 16 + j];
      accM += tile[e * 16 + i] * aj;
      if (i == 0) accS += aj;
    }
    __syncthreads();
  }
  atomicAdd(&Msum[i * 16 + j], accM);
  if (i == 0) atomicAdd(&sumA[j], accS);
}

// ---------- fold bond-linear + BN into WeffbT (bf16, [l][d][k]) + beff ----------
__global__ __launch_bounds__(256) void k_bnfold(
    const float* __restrict__ sumA, const float* __restrict__ Msum,
    const float* __restrict__ bond_W, const float* __restrict__ bond_b,
    const float* __restrict__ bond_g, const float* __restrict__ bond_beta,
    unsigned short* __restrict__ WeffbT, float* __restrict__ beff) {
  __shared__ float Ms[256];
  __shared__ float ab[16];
  int tid = threadIdx.x;
  Ms[tid] = Msum[tid] * (1.f / (float)kE);
  if (tid < 16) ab[tid] = sumA[tid] * (1.f / (float)kE);
  __syncthreads();
  if (tid < 192) {
    int l = tid / 64, d = tid % 64;
    const float* W = bond_W + l * kBF * kD;
    float w[16];
#pragma unroll
    for (int k = 0; k < 16; k++) w[k] = W[k * 64 + d];
    float b = bond_b[l * 64 + d];
    float lin = 0.f;
#pragma unroll
    for (int k = 0; k < 16; k++) lin += ab[k] * w[k];
    float mu = lin + b;
    float q = 0.f;
#pragma unroll
    for (int i = 0; i < 16; i++) {
      float wi = w[i];
#pragma unroll
      for (int k = 0; k < 16; k++) q += Ms[i * 16 + k] * wi * w[k];
    }
    float ex2 = q + 2.f * b * lin + b * b;
    float var = ex2 - mu * mu;
    float s = bond_g[l * 64 + d] * rsqrtf(var + 1e-6f);
#pragma unroll
    for (int k = 0; k < 16; k++)
      WeffbT[(size_t)(l * 64 + d) * 16 + k] = (unsigned short)bf16_bits(w[k] * s);
    beff[l * 64 + d] = (b - mu) * s + bond_beta[l * 64 + d];
  }
}

// ---------- MERGED weight prep: wfold (blocks 0-7) | wlin (8-55) | wprep (56-439) --
// Branch on blockIdx (uniform per block); outputs disjoint; saves 2 dispatches.
__global__ __launch_bounds__(256) void k_prep(
    const float* __restrict__ projW, const float* __restrict__ projb,
    const float* __restrict__ lin_W, const float* __restrict__ lin_b1,
    const float* __restrict__ Wih, const float* __restrict__ Whh,
    unsigned short* __restrict__ WeffTb, float* __restrict__ beff2,
    unsigned short* __restrict__ linWb, unsigned short* __restrict__ Bt) {
  __shared__ float W2[64 * 64];  // used by wfold branch only
  int tid = threadIdx.x;
  int bid = blockIdx.x;
  if (bid < 8) {
    // fold proj + layer-0 linear -> WeffTb (bf16 [out 64][in 128]) + beff2
    for (int i = tid; i < 64 * 64 / 4; i += 256)
      ((float4*)W2)[i] = ((const float4*)lin_W)[i];  // lin_W[0] is first 64x64
    __syncthreads();
    int ccol = tid & 63, rg = tid >> 6;
#pragma unroll
    for (int i = 0; i < 4; i++) {
      int r = bid * 16 + rg + i * 4;
      float s = 0.f;
#pragma unroll 8
      for (int k = 0; k < 64; k++) s += projW[r * 64 + k] * W2[k * 64 + ccol];
      WeffTb[ccol * 128 + r] = (unsigned short)bf16_bits(s);
    }
    if (bid == 0 && tid < 64) {
      float s = lin_b1[tid];
      for (int k = 0; k < 64; k++) s += projb[k] * W2[k * 64 + tid];
      beff2[tid] = s;
    }
  } else if (bid < 56) {
    // lin_W transpose -> bf16 [l][out 64][in 64] (48*256 = 3*64*64 exact)
    int idx = (bid - 8) * 256 + tid;
    int l = idx / 4096, rem = idx % 4096;
    int o = rem / 64, i = rem % 64;
    linWb[idx] = (unsigned short)bf16_bits(lin_W[l * 4096 + i * 64 + o]);
  } else {
    // GRU Bt[l][j][k] bf16; x half (k>=64) in permuted dim order
    int idx = (bid - 56) * 256 + tid;  // 384*256 = 3*256*128 exact
    int l = idx / (256 * 128);
    int rem = idx % (256 * 128);
    int j = rem / 128, k = rem % 128;
    const float* ih = Wih + l * 192 * 64;
    const float* hh = Whh + l * 192 * 64;
    float v;
    if (k < 64) {
      if (j < 192) v = ih[j * 64 + k];
      else         v = 0.f;
    } else {
      int pos = k - 64;
      int kd = (pos & 3) * 16 + (pos >> 2);  // permuted x dim
      if (j < 128)      v = hh[j * 64 + kd];
      else if (j < 192) v = 0.f;
      else              v = hh[(j - 64) * 64 + kd];
    }
    Bt[idx] = (unsigned short)bf16_bits(v);
  }
}

// ---------- MFMA encoder: x = [atom_x | sum_f emb] @ Weff + beff2 ----------
__global__ __launch_bounds__(256) void k_enc3(
    const float* __restrict__ atom_x, const int* __restrict__ feat,
    const float* __restrict__ emb, const unsigned short* __restrict__ WTb,
    const float* __restrict__ beff2, float* __restrict__ xout,
    unsigned short* __restrict__ xb) {
  __shared__ unsigned short A[128 * 128];  // 32 KB
  int tid = threadIdx.x;
  int lane = tid & 63, wv = tid >> 6;
  int nbase = blockIdx.x * 128;
  for (int it = 0; it < 32; it++) {
    int nl = it * 4 + wv;
    int nc = min(nbase + nl, kN - 1);
    float ax = atom_x[(size_t)nc * 64 + lane];
    const int* fr = feat + (size_t)nc * kNF;
    float s = 0.f;
#pragma unroll
    for (int f = 0; f < kNF; f++) s += emb[(f * kCARD + fr[f]) * 64 + lane];
    int swz = (nl & 7) << 3;
    A[(nl * 128 + lane) ^ swz] = (unsigned short)bf16_bits(ax);
    A[(nl * 128 + 64 + lane) ^ swz] = (unsigned short)bf16_bits(s);
  }
  __syncthreads();
  int c = lane & 15, q = lane >> 4;
  int d = wv * 16 + c;
  bf16x8 bfr[4];
#pragma unroll
  for (int kk = 0; kk < 4; kk++) {
    U4BF t;
    t.u = *(const uint4*)(WTb + (size_t)d * 128 + kk * 32 + q * 8);
    bfr[kk] = t.v;
  }
  float bd = beff2[d];
  int perm = c * 4 + wv;  // (d&15)*4 + (d>>4)
  int rswz = (c & 7) << 3;
#pragma unroll 2
  for (int mt = 0; mt < 8; mt++) {
    bf16x8 afr[4];
#pragma unroll
    for (int kk = 0; kk < 4; kk++) {
      U4BF t;
      t.u = *(const uint4*)(A + (((mt * 16 + c) * 128 + kk * 32 + q * 8) ^ rswz));
      afr[kk] = t.v;
    }
    f32x4 a = {bd, bd, bd, bd};
#pragma unroll
    for (int kk = 0; kk < 4; kk++)
      a = __builtin_amdgcn_mfma_f32_16x16x32_bf16(afr[kk], bfr[kk], a, 0, 0, 0);
#pragma unroll
    for (int reg = 0; reg < 4; reg++) {
      int n = nbase + mt * 16 + q * 4 + reg;
      if (n < kN) {
        xout[(size_t)n * 64 + d] = a[reg];
        xb[(size_t)n * 64 + perm] = (unsigned short)bf16_bits(a[reg]);
      }
    }
  }
}

// ---------- MFMA lin (layers 1,2): x = relu(BN(h)) @ lin_W + lin_b ----------
__global__ __launch_bounds__(256) void k_lin3(
    const float* __restrict__ hin, const unsigned short* __restrict__ Wb,
    const float* __restrict__ bg,
    const float* __restrict__ bnsum, const float* __restrict__ bnss,
    const float* __restrict__ bng, const float* __restrict__ bnb,
    float* __restrict__ xout, unsigned short* __restrict__ xb) {
  __shared__ unsigned short A[128 * 64];  // 16 KB
  int tid = threadIdx.x;
  int lane = tid & 63, wv = tid >> 6;
  int nbase = blockIdx.x * 128;
  float m = bnsum[lane] * (1.f / (float)kN);
  float var = bnss[lane] * (1.f / (float)kN) - m * m;
  float sc = rsqrtf(var + 1e-5f) * bng[lane];
  float bb = bnb[lane];
  for (int it = 0; it < 32; it++) {
    int nl = it * 4 + wv;
    int nc = min(nbase + nl, kN - 1);
    float v = hin[(size_t)nc * 64 + lane];
    v = fmaxf((v - m) * sc + bb, 0.f);
    A[(nl * 64 + lane) ^ ((nl & 7) << 3)] = (unsigned short)bf16_bits(v);
  }
  __syncthreads();
  int c = lane & 15, q = lane >> 4;
  int d = wv * 16 + c;
  bf16x8 bfr[2];
#pragma unroll
  for (int kk = 0; kk < 2; kk++) {
    U4BF t;
    t.u = *(const uint4*)(Wb + (size_t)d * 64 + kk * 32 + q * 8);
    bfr[kk] = t.v;
  }
  float bd = bg[d];
  int perm = c * 4 + wv;
  int rswz = (c & 7) << 3;
#pragma unroll 2
  for (int mt = 0; mt < 8; mt++) {
    bf16x8 afr[2];
#pragma unroll
    for (int kk = 0; kk < 2; kk++) {
      U4BF t;
      t.u = *(const uint4*)(A + (((mt * 16 + c) * 64 + kk * 32 + q * 8) ^ rswz));
      afr[kk] = t.v;
    }
    f32x4 a = {bd, bd, bd, bd};
#pragma unroll
    for (int kk = 0; kk < 2; kk++)
      a = __builtin_amdgcn_mfma_f32_16x16x32_bf16(afr[kk], bfr[kk], a, 0, 0, 0);
#pragma unroll
    for (int reg = 0; reg < 4; reg++) {
      int n = nbase + mt * 16 + q * 4 + reg;
      if (n < kN) {
        xout[(size_t)n * 64 + d] = a[reg];
        xb[(size_t)n * 64 + perm] = (unsigned short)bf16_bits(a[reg]);
      }
    }
  }
}

// ---------- CSR gather with MFMA bond: 4 nodes per wave, prologue prefetch ----------
__global__ __launch_bounds__(256) void k_aggr(
    const int* __restrict__ ptr, const int2* __restrict__ re,
    const float* __restrict__ nrm, const unsigned short* __restrict__ ea_s,
    const unsigned short* __restrict__ xb, const unsigned short* __restrict__ WeffbT,
    const float* __restrict__ beff, unsigned short* __restrict__ aggr_b) {
  int lane = threadIdx.x & 63, wv = threadIdx.x >> 6;
  int nb = blockIdx.x * 16 + wv * 4;  // first of 4 nodes for this wave
  if (nb >= kN) return;
  int c = lane & 15, q = lane >> 4;

  U4BF z; z.u = make_uint4(0u, 0u, 0u, 0u);
  bf16x8 bfr[4];
#pragma unroll
  for (int nt = 0; nt < 4; nt++) {
    if (q < 2) {
      U4BF t;
      t.u = *(const uint4*)(WeffbT + (size_t)(nt * 16 + c) * 16 + q * 8);
      bfr[nt] = t.v;
    } else {
      bfr[nt] = z.v;
    }
  }
  float be4[4];
#pragma unroll
  for (int nt = 0; nt < 4; nt++) be4[nt] = beff[nt * 16 + c];
  const char* xcol = (const char*)xb + (c << 3);  // lane's 8B slice base
  const f32x2 zero2 = {0.f, 0.f};

  // prologue: ranges (uniform/scalar) + first-window re/nrm for all 4 nodes
  int st[4], en[4];
#pragma unroll
  for (int i = 0; i < 4; i++) {
    bool ok = (nb + i) < kN;
    st[i] = ok ? ptr[nb + i] : 0;
    en[i] = ok ? ptr[nb + i + 1] : 0;
  }
  int2 m0[4];
  float nr0[4];
#pragma unroll
  for (int i = 0; i < 4; i++) {
    int j = st[i] + lane;
    bool val = j < en[i];
    m0[i] = val ? re[j] : make_int2(0, 0);
    nr0[i] = val ? nrm[j] : 0.f;
  }

  for (int i = 0; i < 4; i++) {
    int n = nb + i;
    if (n >= kN) break;
    int start = st[i], end = en[i];
    f32x2 p01 = zero2, p23 = zero2;  // dims {c,16+c} and {32+c,48+c} partials
    int2 m = m0[i];
    float nr = nr0[i];

    for (int j0 = start; j0 < end; j0 += 64) {
      if (j0 != start) {  // windows >=1 (rare at avg degree 16)
        int j = j0 + lane;
        bool val = j < end;
        m = val ? re[j] : make_int2(0, 0);
        nr = val ? nrm[j] : 0.f;
      }
      int cnt = min(64, end - j0);
      int mts = (cnt + 15) >> 4;
      for (int mt = 0; mt < mts; mt++) {
        bf16x8 afr;
        if (q < 2) {
          U4BF t;
          t.u = *(const uint4*)(ea_s + (size_t)(j0 + mt * 16 + c) * 16 + q * 8);
          afr = t.v;
        } else {
          afr = z.v;
        }
        f32x4 bond[4];
#pragma unroll
        for (int nt = 0; nt < 4; nt++) {
          f32x4 a = {be4[nt], be4[nt], be4[nt], be4[nt]};
          bond[nt] = __builtin_amdgcn_mfma_f32_16x16x32_bf16(afr, bfr[nt], a, 0, 0, 0);
        }
#pragma unroll
        for (int reg = 0; reg < 4; reg++) {
          int el = mt * 16 + (q << 2) + reg;
          int rt = __builtin_amdgcn_ds_bpermute(el << 2, m.x);  // byte offset
          float nv = __uint_as_float(
              (unsigned)__builtin_amdgcn_ds_bpermute(el << 2, (int)__float_as_uint(nr)));
          uint2 xw = *(const uint2*)(xcol + rt);
          f32x2 xva = {__uint_as_float(xw.x << 16),
                       __uint_as_float(xw.x & 0xffff0000u)};
          f32x2 xvb = {__uint_as_float(xw.y << 16),
                       __uint_as_float(xw.y & 0xffff0000u)};
          f32x2 ba = {bond[0][reg], bond[1][reg]};
          f32x2 bb = {bond[2][reg], bond[3][reg]};
          f32x2 ta = __builtin_elementwise_max(xva + ba, zero2);
          f32x2 tb = __builtin_elementwise_max(xvb + bb, zero2);
          f32x2 nv2 = {nv, nv};
          p01 += nv2 * ta;
          p23 += nv2 * tb;
        }
      }
    }
    // reduce partials across quads (lanes c, c+16, c+32, c+48 share dims)
    float pa0 = p01.x, pa1 = p01.y, pa2 = p23.x, pa3 = p23.y;
    pa0 += __shfl_xor(pa0, 16, 64); pa0 += __shfl_xor(pa0, 32, 64);
    pa1 += __shfl_xor(pa1, 16, 64); pa1 += __shfl_xor(pa1, 32, 64);
    pa2 += __shfl_xor(pa2, 16, 64); pa2 += __shfl_xor(pa2, 32, 64);
    pa3 += __shfl_xor(pa3, 16, 64); pa3 += __shfl_xor(pa3, 32, 64);
    float outv = (q == 0) ? pa0 : (q == 1) ? pa1 : (q == 2) ? pa2 : pa3;
    aggr_b[(size_t)n * 64 + lane] = (unsigned short)bf16_bits(outv);
  }
}

// ---------- MFMA GRU, register-blocked B: wave w = dim chunk, all 4 gates ----------
__global__ __launch_bounds__(256) void k_gru_mfma(
    const unsigned short* __restrict__ aggr_b, const unsigned short* __restrict__ xb,
    const float* __restrict__ x, const unsigned short* __restrict__ Bt,
    const float* __restrict__ bih, const float* __restrict__ bhh,
    const float* __restrict__ root, const float* __restrict__ degf,
    float* __restrict__ h, float* __restrict__ bnsum, float* __restrict__ bnss) {
  int tid = threadIdx.x;
  int w = tid >> 6;
  int lane = tid & 63;
  int c = lane & 15, q = lane >> 4;
  int nbase = blockIdx.x * 128;
  int d = w * 16 + c;

  bf16x8 bfr[4][4];
#pragma unroll
  for (int g = 0; g < 4; g++)
#pragma unroll
    for (int kk = 0; kk < 4; kk++) {
      U4BF t;
      t.u = *(const uint4*)(Bt + (size_t)((g * 4 + w) * 16 + c) * 128 + kk * 32 + q * 8);
      bfr[g][kk] = t.v;
    }

  float br = bih[d] + bhh[d];
  float bz = bih[64 + d] + bhh[64 + d];
  float bin = bih[128 + d];
  float bhn = bhh[128 + d];
  float rt = root[d];
  float s1 = 0.f, s2 = 0.f;

#pragma unroll 2
  for (int mt = 0; mt < 8; mt++) {
    int na = nbase + mt * 16 + c;
    int nac = min(na, kN - 1);
    bf16x8 afr[4];
#pragma unroll
    for (int kk = 0; kk < 4; kk++) {
      const unsigned short* src = (kk < 2)
          ? aggr_b + (size_t)nac * 64 + kk * 32 + q * 8
          : xb + (size_t)nac * 64 + (kk - 2) * 32 + q * 8;
      U4BF t;
      t.u = *(const uint4*)src;
      afr[kk] = t.v;
    }
    f32x4 acc[4];
#pragma unroll
    for (int g = 0; g < 4; g++) {
      f32x4 a = {0.f, 0.f, 0.f, 0.f};
#pragma unroll
      for (int kk = 0; kk < 4; kk++)
        a = __builtin_amdgcn_mfma_f32_16x16x32_bf16(afr[kk], bfr[g][kk], a, 0, 0, 0);
      acc[g] = a;
    }
#pragma unroll
    for (int reg = 0; reg < 4; reg++) {
      int n = nbase + mt * 16 + q * 4 + reg;
      if (n < kN) {
        float xv = x[(size_t)n * 64 + d];
        float r = sigm(acc[0][reg] + br);
        float zz = sigm(acc[1][reg] + bz);
        float nn = tanh_f(acc[2][reg] + bin + r * (acc[3][reg] + bhn));
        float upd = (1.f - zz) * nn + zz * xv;
        float hl = upd + fmaxf(xv + rt, 0.f) / degf[n];
        h[(size_t)n * 64 + d] = hl;
        s1 += hl;
        s2 += hl * hl;
      }
    }
  }
  s1 += __shfl_xor(s1, 16, 64);
  s1 += __shfl_xor(s1, 32, 64);
  s2 += __shfl_xor(s2, 16, 64);
  s2 += __shfl_xor(s2, 32, 64);
  if (q == 0) {
    atomicAdd(&bnsum[d], s1);
    atomicAdd(&bnss[d], s2);
  }
}

// ---------- final BN (layer 2, no relu) -> d_out ----------
__global__ void k_final(const float* __restrict__ h, const float* __restrict__ bnsum,
                        const float* __restrict__ bnss, const float* __restrict__ bng,
                        const float* __restrict__ bnb, float* __restrict__ out) {
  int idx = blockIdx.x * blockDim.x + threadIdx.x;
  if (idx < kN * kD) {
    int d = idx & 63;
    float m = bnsum[d] * (1.f / (float)kN);
    float var = bnss[d] * (1.f / (float)kN) - m * m;
    float sc = rsqrtf(var + 1e-5f) * bng[d];
    out[idx] = (h[idx] - m) * sc + bnb[d];
  }
}

extern "C" void kernel_launch(void* const* d_in, const int* in_sizes, int n_in,
                              void* d_out, int out_size, void* d_ws, size_t ws_size,
                              hipStream_t stream) {
  const float* atom_x       = (const float*)d_in[0];
  const int*   atom_feature = (const int*)d_in[1];
  const int*   edge_index   = (const int*)d_in[2];
  const float* edge_attr    = (const float*)d_in[3];
  const float* atom_emb     = (const float*)d_in[4];
  const float* proj_W       = (const float*)d_in[5];
  const float* proj_b       = (const float*)d_in[6];
  const float* lin_W        = (const float*)d_in[7];
  const float* lin_b        = (const float*)d_in[8];
  const float* root_emb     = (const float*)d_in[9];
  const float* bond_W       = (const float*)d_in[10];
  const float* bond_b       = (const float*)d_in[11];
  const float* bond_g       = (const float*)d_in[12];
  const float* bond_beta    = (const float*)d_in[13];
  const float* gru_Wih      = (const float*)d_in[14];
  const float* gru_bih      = (const float*)d_in[15];
  const float* gru_Whh      = (const float*)d_in[16];
  const float* gru_bhh      = (const float*)d_in[17];
  const float* bn_g         = (const float*)d_in[18];
  const float* bn_b         = (const float*)d_in[19];
  float* out = (float*)d_out;

  const int* row = edge_index;
  const int* col = edge_index + kE;

  float* ws = (float*)d_ws;
  const size_t NH = (size_t)kN * kD;
  float* h     = ws;                         // NH
  float* x     = h + NH;                     // NH
  float* degf  = x + NH;                     // kN
  float* dinv  = degf + kN;                  // kN
  int*   cntr  = (int*)(dinv + kN);          // kN (reused: folded weights)
  int*   cntc  = cntr + kN;                  // kN
  int*   ptr   = cntc + kN;                  // kN+1 (reserve kN+4)
  int*   fill  = ptr + kN + 4;               // kN (unused, layout keep)
  int*   loc   = fill + kN;                  // kN
  int*   bsum  = loc + kN;                   // 128
  int*   boff  = bsum + 128;                 // 128
  int2*  re    = (int2*)(boff + 128);        // kE int2
  float* nrm   = (float*)(re + kE);          // kE
  unsigned short* ea_s   = (unsigned short*)(nrm + kE);      // kE*16 + 1024 pad
  unsigned short* xb     = ea_s + (size_t)kE * 16 + 1024;    // N*64
  unsigned short* aggr_b = xb + (size_t)kN * 64;             // N*64
  unsigned short* Bt     = aggr_b + (size_t)kN * 64;         // 3*256*128
  unsigned short* WeffbT = Bt + 3 * 256 * 128;               // 3*64*16
  float* sumA  = (float*)(WeffbT + 3 * 64 * 16);  // 16
  float* Msum  = sumA + 16;                  // 256
  float* bnsum = Msum + 256;                 // 192 (3 layers x 64)
  float* bnss  = bnsum + 192;                // 192
  float* beff  = bnss + 192;                 // 192 (NOT zeroed; k_bnfold writes)

  // folded weights live in the (otherwise unused) cntr region
  unsigned short* WeffTb = (unsigned short*)cntr;          // 64*128 u16
  float* beff2 = (float*)(WeffTb + 64 * 128);              // 64 floats
  unsigned short* linWb  = (unsigned short*)(beff2 + 64);  // 3*64*64 u16

  // histogram partials live in the x region (12.8 MB; x dead until k_enc3)
  unsigned short* part = (unsigned short*)x;

  k_prep<<<440, 256, 0, stream>>>(proj_W, proj_b, lin_W, lin_b, gru_Wih, gru_Whh,
                                  WeffTb, beff2, linWb, Bt);
  k_hist<<<kHC * kHS, 256, 0, stream>>>(row, col, part);
  k_hmerge<<<(kN + 255) / 256, 256, 0, stream>>>(part, degf, dinv, cntc);
  k_scanA<<<kScanBlocks, 1024, 0, stream>>>(cntc, loc, bsum);
  k_scanB<<<1, 128, 0, stream>>>(bsum, boff);
  k_scanC<<<kScanBlocks, 1024, 0, stream>>>(loc, boff, ptr);
  k_scatter2<<<kHC * kHS, 256, 0, stream>>>(row, col, dinv, ptr, part, re, nrm);
  k_gea<<<(kE * 4 + 255) / 256, 256, 0, stream>>>(re, edge_attr, ea_s);

  // zero sumA+Msum+bnsum+bnss (656 floats) once; per-layer BN slabs replace
  // the 3 in-loop memset dispatches.
  hipMemsetAsync(sumA, 0, (16 + 256 + 192 + 192) * sizeof(float), stream);
  k_stats<<<512, 256, 0, stream>>>(edge_attr, sumA, Msum);
  k_bnfold<<<1, 256, 0, stream>>>(sumA, Msum, bond_W, bond_b, bond_g, bond_beta,
                                  WeffbT, beff);
  k_enc3<<<kNB, 256, 0, stream>>>(atom_x, atom_feature, atom_emb, WeffTb, beff2,
                                  x, xb);

  for (int l = 0; l < 3; l++) {
    if (l > 0) {
      k_lin3<<<kNB, 256, 0, stream>>>(h, linWb + (size_t)l * 4096, lin_b + l * 64,
                                      bnsum + (l - 1) * 64, bnss + (l - 1) * 64,
                                      bn_g + (l - 1) * 64, bn_b + (l - 1) * 64,
                                      x, xb);
    }
    k_aggr<<<(kN + 15) / 16, 256, 0, stream>>>(ptr, re, nrm, ea_s, xb,
                                               WeffbT + (size_t)l * 64 * 16,
                                               beff + l * 64, aggr_b);
    k_gru_mfma<<<(kN + 127) / 128, 256, 0, stream>>>(
        aggr_b, xb, x, Bt + (size_t)l * 256 * 128, gru_bih + l * 192,
        gru_bhh + l * 192, root_emb + l * 64, degf, h,
        bnsum + l * 64, bnss + l * 64);
  }
  k_final<<<(kN * kD + 255) / 256, 256, 0, stream>>>(h, bnsum + 128, bnss + 128,
                                                     bn_g + 2 * 64, bn_b + 2 * 64,
                                                     out);
}

// Round 16
// 975.295 us; speedup vs baseline: 1.0499x; 1.0151x over previous
//
#include <hip/hip_runtime.h>
#include <hip/hip_bf16.h>

constexpr int kN    = 100000;
constexpr int kE    = 1600000;
constexpr int kD    = 64;
constexpr int kNF   = 9;
constexpr int kCARD = 16;
constexpr int kBF   = 16;
constexpr int kScanBlocks = (kN + 1023) / 1024;  // 98
constexpr int kNB   = (kN + 127) / 128;          // 782 node blocks

// histogram privatization geometry
constexpr int kHC    = 8;             // node chunks
constexpr int kHS    = 64;            // edge slices
constexpr int kChunk = kN / kHC;      // 12500 nodes per chunk
constexpr int kSlice = kE / kHS;      // 25000 edges per slice

typedef __bf16 bf16x8 __attribute__((ext_vector_type(8)));
typedef float f32x4 __attribute__((ext_vector_type(4)));
typedef float f32x2 __attribute__((ext_vector_type(2)));
union U4BF { uint4 u; bf16x8 v; };

__device__ __forceinline__ float sigm(float v) { return 1.f / (1.f + __expf(-v)); }
__device__ __forceinline__ float tanh_f(float v) { return 1.f - 2.f / (__expf(2.f * v) + 1.f); }

__device__ __forceinline__ unsigned bf16_bits(float v) {
  unsigned u = __float_as_uint(v);
  return (u + 0x7fffu + ((u >> 16) & 1u)) >> 16;
}

// ---------- privatized degree histogram: block (c,s) counts chunk c over slice s ----
__global__ __launch_bounds__(256) void k_hist(const int* __restrict__ row,
                                              const int* __restrict__ col,
                                              unsigned short* __restrict__ part) {
  __shared__ unsigned bins[kChunk];  // 50 KB
  int tid = threadIdx.x;
  int c = blockIdx.x / kHS, s = blockIdx.x % kHS;
  int nlo = c * kChunk;
  for (int i = tid; i < kChunk; i += 256) bins[i] = 0u;
  __syncthreads();
  int e0 = s * kSlice;
  for (int i = tid; i < kSlice; i += 256) {
    int r = row[e0 + i];
    int cc = col[e0 + i];
    unsigned ur = (unsigned)(r - nlo);
    unsigned uc = (unsigned)(cc - nlo);
    if (ur < (unsigned)kChunk) atomicAdd(&bins[ur], 1u);
    if (uc < (unsigned)kChunk) atomicAdd(&bins[uc], 0x10000u);
  }
  __syncthreads();
  unsigned short* dst = part + (size_t)blockIdx.x * kChunk;
  for (int i = tid; i < kChunk; i += 256) {
    unsigned v = bins[i];
    dst[i] = (unsigned short)((v & 0xffu) | ((v >> 8) & 0xff00u));
  }
}

// ---------- MERGED hmerge + scanA: per-node column merge of part (rewriting it with
// the exclusive col prefix), degf/dinv write, then block-local exclusive scan ----
__global__ __launch_bounds__(1024) void k_scanA(
    unsigned short* __restrict__ part, float* __restrict__ degf,
    float* __restrict__ dinv, int* __restrict__ loc, int* __restrict__ bsum) {
  __shared__ int pl[1024];
  int tid = threadIdx.x;
  int n = blockIdx.x * 1024 + tid;
  int v = 0;
  if (n < kN) {
    int c = n / kChunk, j = n % kChunk;
    unsigned short* p = part + (size_t)c * kHS * kChunk + j;
    unsigned sr = 0, run = 0;
#pragma unroll
    for (int s = 0; s < kHS; s++) {
      unsigned vv = p[(size_t)s * kChunk];
      p[(size_t)s * kChunk] = (unsigned short)run;  // exclusive col prefix
      run += vv >> 8;
      sr += vv & 0xffu;
    }
    float d = (float)sr + 1.f;
    degf[n] = d;
    dinv[n] = rsqrtf(d);
    v = (int)run;
  }
  pl[tid] = v;
  __syncthreads();
  for (int off = 1; off < 1024; off <<= 1) {
    int t = (tid >= off) ? pl[tid - off] : 0;
    __syncthreads();
    pl[tid] += t;
    __syncthreads();
  }
  if (n < kN) loc[n] = pl[tid] - v;  // local exclusive
  if (tid == 1023) bsum[blockIdx.x] = pl[1023];
}

__global__ __launch_bounds__(128) void k_scanB(const int* __restrict__ bsum,
                                               int* __restrict__ boff) {
  __shared__ int p[128];
  int tid = threadIdx.x;
  int v = (tid < kScanBlocks) ? bsum[tid] : 0;
  p[tid] = v;
  __syncthreads();
  for (int off = 1; off < 128; off <<= 1) {
    int t = (tid >= off) ? p[tid - off] : 0;
    __syncthreads();
    p[tid] += t;
    __syncthreads();
  }
  boff[tid] = p[tid] - v;  // exclusive
}

__global__ __launch_bounds__(1024) void k_scanC(const int* __restrict__ loc,
                                                const int* __restrict__ boff,
                                                int* __restrict__ ptr) {
  int i = blockIdx.x * 1024 + threadIdx.x;
  if (i < kN) ptr[i] = loc[i] + boff[blockIdx.x];
  if (i == 0) ptr[kN] = kE;  // grand total is statically kE
}

// ---------- scatter via LDS offsets (zero global atomics) ----------
// re.x stores the PRE-SCALED xb byte offset (r << 7); re.y the edge id.
__global__ __launch_bounds__(256) void k_scatter2(
    const int* __restrict__ row, const int* __restrict__ col,
    const float* __restrict__ dinv, const int* __restrict__ ptr,
    const unsigned short* __restrict__ part,
    int2* __restrict__ re, float* __restrict__ nrm) {
  __shared__ unsigned bins[kChunk];  // 50 KB
  int tid = threadIdx.x;
  int c = blockIdx.x / kHS, s = blockIdx.x % kHS;
  int nlo = c * kChunk;
  const unsigned short* pp = part + (size_t)blockIdx.x * kChunk;
  for (int i = tid; i < kChunk; i += 256)
    bins[i] = (unsigned)ptr[nlo + i] + (unsigned)pp[i];
  __syncthreads();
  int e0 = s * kSlice;
  for (int i = tid; i < kSlice; i += 256) {
    int e = e0 + i;
    int cc = col[e];
    unsigned uc = (unsigned)(cc - nlo);
    if (uc < (unsigned)kChunk) {
      int r = row[e];
      int p = (int)atomicAdd(&bins[uc], 1u);
      re[p] = make_int2(r << 7, e);
      nrm[p] = dinv[r] * dinv[cc];
    }
  }
}

// ---------- MERGED gea + stats: edge_attr -> bf16 CSR order AND moments ----------
// Grid-stride over 64-edge groups (re order is a permutation of all edges, and
// sum/A^T A are order-independent -> identical stats up to atomic reordering).
// Deletes k_stats' separate 102MB edge_attr re-read.
__global__ __launch_bounds__(256) void k_gea(
    const int2* __restrict__ re, const float* __restrict__ ea,
    unsigned short* __restrict__ ea_s, float* __restrict__ sumA,
    float* __restrict__ Msum) {
  __shared__ float tile[1024];  // 64 edges x 16 dims
  int tid = threadIdx.x;
  int i = tid >> 4, j = tid & 15;
  int es = tid >> 2, cq = tid & 3;  // edge slot (0..63), quarter (0..3)
  float accM = 0.f, accS = 0.f;
  const int T = kE / 64;  // 25000 groups, exact
  for (int t = blockIdx.x; t < T; t += gridDim.x) {
    int p = t * 64 + es;
    int e = re[p].y;
    float4 v = *(const float4*)(ea + (size_t)e * 16 + cq * 4);
    ushort4 o;
    o.x = (unsigned short)bf16_bits(v.x);
    o.y = (unsigned short)bf16_bits(v.y);
    o.z = (unsigned short)bf16_bits(v.z);
    o.w = (unsigned short)bf16_bits(v.w);
    *(ushort4*)(ea_s + (size_t)p * 16 + cq * 4) = o;
    *(float4*)(tile + es * 16 + cq * 4) = v;
    __syncthreads();
#pragma unroll 8
    for (int e2 = 0; e2 < 64; e2++) {
      float aj = tile[e2 * 16 + j];
      accM += tile[e2 * 16 + i] * aj;
      if (i == 0) accS += aj;
    }
    __syncthreads();
  }
  atomicAdd(&Msum[i * 16 + j], accM);
  if (i == 0) atomicAdd(&sumA[j], accS);
}

// ---------- fold bond-linear + BN into WeffbT (bf16, [l][d][k]) + beff ----------
__global__ __launch_bounds__(256) void k_bnfold(
    const float* __restrict__ sumA, const float* __restrict__ Msum,
    const float* __restrict__ bond_W, const float* __restrict__ bond_b,
    const float* __restrict__ bond_g, const float* __restrict__ bond_beta,
    unsigned short* __restrict__ WeffbT, float* __restrict__ beff) {
  __shared__ float Ms[256];
  __shared__ float ab[16];
  int tid = threadIdx.x;
  Ms[tid] = Msum[tid] * (1.f / (float)kE);
  if (tid < 16) ab[tid] = sumA[tid] * (1.f / (float)kE);
  __syncthreads();
  if (tid < 192) {
    int l = tid / 64, d = tid % 64;
    const float* W = bond_W + l * kBF * kD;
    float w[16];
#pragma unroll
    for (int k = 0; k < 16; k++) w[k] = W[k * 64 + d];
    float b = bond_b[l * 64 + d];
    float lin = 0.f;
#pragma unroll
    for (int k = 0; k < 16; k++) lin += ab[k] * w[k];
    float mu = lin + b;
    float q = 0.f;
#pragma unroll
    for (int i = 0; i < 16; i++) {
      float wi = w[i];
#pragma unroll
      for (int k = 0; k < 16; k++) q += Ms[i * 16 + k] * wi * w[k];
    }
    float ex2 = q + 2.f * b * lin + b * b;
    float var = ex2 - mu * mu;
    float s = bond_g[l * 64 + d] * rsqrtf(var + 1e-6f);
#pragma unroll
    for (int k = 0; k < 16; k++)
      WeffbT[(size_t)(l * 64 + d) * 16 + k] = (unsigned short)bf16_bits(w[k] * s);
    beff[l * 64 + d] = (b - mu) * s + bond_beta[l * 64 + d];
  }
}

// ---------- MERGED weight prep: wfold (blocks 0-7) | wlin (8-55) | wprep (56-439) --
__global__ __launch_bounds__(256) void k_prep(
    const float* __restrict__ projW, const float* __restrict__ projb,
    const float* __restrict__ lin_W, const float* __restrict__ lin_b1,
    const float* __restrict__ Wih, const float* __restrict__ Whh,
    unsigned short* __restrict__ WeffTb, float* __restrict__ beff2,
    unsigned short* __restrict__ linWb, unsigned short* __restrict__ Bt) {
  __shared__ float W2[64 * 64];  // used by wfold branch only
  int tid = threadIdx.x;
  int bid = blockIdx.x;
  if (bid < 8) {
    for (int i = tid; i < 64 * 64 / 4; i += 256)
      ((float4*)W2)[i] = ((const float4*)lin_W)[i];  // lin_W[0] is first 64x64
    __syncthreads();
    int ccol = tid & 63, rg = tid >> 6;
#pragma unroll
    for (int i = 0; i < 4; i++) {
      int r = bid * 16 + rg + i * 4;
      float s = 0.f;
#pragma unroll 8
      for (int k = 0; k < 64; k++) s += projW[r * 64 + k] * W2[k * 64 + ccol];
      WeffTb[ccol * 128 + r] = (unsigned short)bf16_bits(s);
    }
    if (bid == 0 && tid < 64) {
      float s = lin_b1[tid];
      for (int k = 0; k < 64; k++) s += projb[k] * W2[k * 64 + tid];
      beff2[tid] = s;
    }
  } else if (bid < 56) {
    int idx = (bid - 8) * 256 + tid;
    int l = idx / 4096, rem = idx % 4096;
    int o = rem / 64, i = rem % 64;
    linWb[idx] = (unsigned short)bf16_bits(lin_W[l * 4096 + i * 64 + o]);
  } else {
    int idx = (bid - 56) * 256 + tid;  // 384*256 = 3*256*128 exact
    int l = idx / (256 * 128);
    int rem = idx % (256 * 128);
    int j = rem / 128, k = rem % 128;
    const float* ih = Wih + l * 192 * 64;
    const float* hh = Whh + l * 192 * 64;
    float v;
    if (k < 64) {
      if (j < 192) v = ih[j * 64 + k];
      else         v = 0.f;
    } else {
      int pos = k - 64;
      int kd = (pos & 3) * 16 + (pos >> 2);  // permuted x dim
      if (j < 128)      v = hh[j * 64 + kd];
      else if (j < 192) v = 0.f;
      else              v = hh[(j - 64) * 64 + kd];
    }
    Bt[idx] = (unsigned short)bf16_bits(v);
  }
}

// ---------- MFMA encoder: x = [atom_x | sum_f emb] @ Weff + beff2 ----------
__global__ __launch_bounds__(256) void k_enc3(
    const float* __restrict__ atom_x, const int* __restrict__ feat,
    const float* __restrict__ emb, const unsigned short* __restrict__ WTb,
    const float* __restrict__ beff2, float* __restrict__ xout,
    unsigned short* __restrict__ xb) {
  __shared__ unsigned short A[128 * 128];  // 32 KB
  int tid = threadIdx.x;
  int lane = tid & 63, wv = tid >> 6;
  int nbase = blockIdx.x * 128;
  for (int it = 0; it < 32; it++) {
    int nl = it * 4 + wv;
    int nc = min(nbase + nl, kN - 1);
    float ax = atom_x[(size_t)nc * 64 + lane];
    const int* fr = feat + (size_t)nc * kNF;
    float s = 0.f;
#pragma unroll
    for (int f = 0; f < kNF; f++) s += emb[(f * kCARD + fr[f]) * 64 + lane];
    int swz = (nl & 7) << 3;
    A[(nl * 128 + lane) ^ swz] = (unsigned short)bf16_bits(ax);
    A[(nl * 128 + 64 + lane) ^ swz] = (unsigned short)bf16_bits(s);
  }
  __syncthreads();
  int c = lane & 15, q = lane >> 4;
  int d = wv * 16 + c;
  bf16x8 bfr[4];
#pragma unroll
  for (int kk = 0; kk < 4; kk++) {
    U4BF t;
    t.u = *(const uint4*)(WTb + (size_t)d * 128 + kk * 32 + q * 8);
    bfr[kk] = t.v;
  }
  float bd = beff2[d];
  int perm = c * 4 + wv;  // (d&15)*4 + (d>>4)
  int rswz = (c & 7) << 3;
#pragma unroll 2
  for (int mt = 0; mt < 8; mt++) {
    bf16x8 afr[4];
#pragma unroll
    for (int kk = 0; kk < 4; kk++) {
      U4BF t;
      t.u = *(const uint4*)(A + (((mt * 16 + c) * 128 + kk * 32 + q * 8) ^ rswz));
      afr[kk] = t.v;
    }
    f32x4 a = {bd, bd, bd, bd};
#pragma unroll
    for (int kk = 0; kk < 4; kk++)
      a = __builtin_amdgcn_mfma_f32_16x16x32_bf16(afr[kk], bfr[kk], a, 0, 0, 0);
#pragma unroll
    for (int reg = 0; reg < 4; reg++) {
      int n = nbase + mt * 16 + q * 4 + reg;
      if (n < kN) {
        xout[(size_t)n * 64 + d] = a[reg];
        xb[(size_t)n * 64 + perm] = (unsigned short)bf16_bits(a[reg]);
      }
    }
  }
}

// ---------- MFMA lin (layers 1,2): x = relu(BN(h)) @ lin_W + lin_b ----------
__global__ __launch_bounds__(256) void k_lin3(
    const float* __restrict__ hin, const unsigned short* __restrict__ Wb,
    const float* __restrict__ bg,
    const float* __restrict__ bnsum, const float* __restrict__ bnss,
    const float* __restrict__ bng, const float* __restrict__ bnb,
    float* __restrict__ xout, unsigned short* __restrict__ xb) {
  __shared__ unsigned short A[128 * 64];  // 16 KB
  int tid = threadIdx.x;
  int lane = tid & 63, wv = tid >> 6;
  int nbase = blockIdx.x * 128;
  float m = bnsum[lane] * (1.f / (float)kN);
  float var = bnss[lane] * (1.f / (float)kN) - m * m;
  float sc = rsqrtf(var + 1e-5f) * bng[lane];
  float bb = bnb[lane];
  for (int it = 0; it < 32; it++) {
    int nl = it * 4 + wv;
    int nc = min(nbase + nl, kN - 1);
    float v = hin[(size_t)nc * 64 + lane];
    v = fmaxf((v - m) * sc + bb, 0.f);
    A[(nl * 64 + lane) ^ ((nl & 7) << 3)] = (unsigned short)bf16_bits(v);
  }
  __syncthreads();
  int c = lane & 15, q = lane >> 4;
  int d = wv * 16 + c;
  bf16x8 bfr[2];
#pragma unroll
  for (int kk = 0; kk < 2; kk++) {
    U4BF t;
    t.u = *(const uint4*)(Wb + (size_t)d * 64 + kk * 32 + q * 8);
    bfr[kk] = t.v;
  }
  float bd = bg[d];
  int perm = c * 4 + wv;
  int rswz = (c & 7) << 3;
#pragma unroll 2
  for (int mt = 0; mt < 8; mt++) {
    bf16x8 afr[2];
#pragma unroll
    for (int kk = 0; kk < 2; kk++) {
      U4BF t;
      t.u = *(const uint4*)(A + (((mt * 16 + c) * 64 + kk * 32 + q * 8) ^ rswz));
      afr[kk] = t.v;
    }
    f32x4 a = {bd, bd, bd, bd};
#pragma unroll
    for (int kk = 0; kk < 2; kk++)
      a = __builtin_amdgcn_mfma_f32_16x16x32_bf16(afr[kk], bfr[kk], a, 0, 0, 0);
#pragma unroll
    for (int reg = 0; reg < 4; reg++) {
      int n = nbase + mt * 16 + q * 4 + reg;
      if (n < kN) {
        xout[(size_t)n * 64 + d] = a[reg];
        xb[(size_t)n * 64 + perm] = (unsigned short)bf16_bits(a[reg]);
      }
    }
  }
}

// ---------- CSR gather with MFMA bond: 4 nodes per wave, prologue prefetch ----------
__global__ __launch_bounds__(256) void k_aggr(
    const int* __restrict__ ptr, const int2* __restrict__ re,
    const float* __restrict__ nrm, const unsigned short* __restrict__ ea_s,
    const unsigned short* __restrict__ xb, const unsigned short* __restrict__ WeffbT,
    const float* __restrict__ beff, unsigned short* __restrict__ aggr_b) {
  int lane = threadIdx.x & 63, wv = threadIdx.x >> 6;
  int nb = blockIdx.x * 16 + wv * 4;  // first of 4 nodes for this wave
  if (nb >= kN) return;
  int c = lane & 15, q = lane >> 4;

  U4BF z; z.u = make_uint4(0u, 0u, 0u, 0u);
  bf16x8 bfr[4];
#pragma unroll
  for (int nt = 0; nt < 4; nt++) {
    if (q < 2) {
      U4BF t;
      t.u = *(const uint4*)(WeffbT + (size_t)(nt * 16 + c) * 16 + q * 8);
      bfr[nt] = t.v;
    } else {
      bfr[nt] = z.v;
    }
  }
  float be4[4];
#pragma unroll
  for (int nt = 0; nt < 4; nt++) be4[nt] = beff[nt * 16 + c];
  const char* xcol = (const char*)xb + (c << 3);  // lane's 8B slice base
  const f32x2 zero2 = {0.f, 0.f};

  // prologue: ranges (uniform/scalar) + first-window re/nrm for all 4 nodes
  int st[4], en[4];
#pragma unroll
  for (int i = 0; i < 4; i++) {
    bool ok = (nb + i) < kN;
    st[i] = ok ? ptr[nb + i] : 0;
    en[i] = ok ? ptr[nb + i + 1] : 0;
  }
  int2 m0[4];
  float nr0[4];
#pragma unroll
  for (int i = 0; i < 4; i++) {
    int j = st[i] + lane;
    bool val = j < en[i];
    m0[i] = val ? re[j] : make_int2(0, 0);
    nr0[i] = val ? nrm[j] : 0.f;
  }

  for (int i = 0; i < 4; i++) {
    int n = nb + i;
    if (n >= kN) break;
    int start = st[i], end = en[i];
    f32x2 p01 = zero2, p23 = zero2;  // dims {c,16+c} and {32+c,48+c} partials
    int2 m = m0[i];
    float nr = nr0[i];

    for (int j0 = start; j0 < end; j0 += 64) {
      if (j0 != start) {  // windows >=1 (rare at avg degree 16)
        int j = j0 + lane;
        bool val = j < end;
        m = val ? re[j] : make_int2(0, 0);
        nr = val ? nrm[j] : 0.f;
      }
      int cnt = min(64, end - j0);
      int mts = (cnt + 15) >> 4;
      for (int mt = 0; mt < mts; mt++) {
        bf16x8 afr;
        if (q < 2) {
          U4BF t;
          t.u = *(const uint4*)(ea_s + (size_t)(j0 + mt * 16 + c) * 16 + q * 8);
          afr = t.v;
        } else {
          afr = z.v;
        }
        f32x4 bond[4];
#pragma unroll
        for (int nt = 0; nt < 4; nt++) {
          f32x4 a = {be4[nt], be4[nt], be4[nt], be4[nt]};
          bond[nt] = __builtin_amdgcn_mfma_f32_16x16x32_bf16(afr, bfr[nt], a, 0, 0, 0);
        }
#pragma unroll
        for (int reg = 0; reg < 4; reg++) {
          int el = mt * 16 + (q << 2) + reg;
          int rt = __builtin_amdgcn_ds_bpermute(el << 2, m.x);  // byte offset
          float nv = __uint_as_float(
              (unsigned)__builtin_amdgcn_ds_bpermute(el << 2, (int)__float_as_uint(nr)));
          uint2 xw = *(const uint2*)(xcol + rt);
          f32x2 xva = {__uint_as_float(xw.x << 16),
                       __uint_as_float(xw.x & 0xffff0000u)};
          f32x2 xvb = {__uint_as_float(xw.y << 16),
                       __uint_as_float(xw.y & 0xffff0000u)};
          f32x2 ba = {bond[0][reg], bond[1][reg]};
          f32x2 bb = {bond[2][reg], bond[3][reg]};
          f32x2 ta = __builtin_elementwise_max(xva + ba, zero2);
          f32x2 tb = __builtin_elementwise_max(xvb + bb, zero2);
          f32x2 nv2 = {nv, nv};
          p01 += nv2 * ta;
          p23 += nv2 * tb;
        }
      }
    }
    // reduce partials across quads (lanes c, c+16, c+32, c+48 share dims)
    float pa0 = p01.x, pa1 = p01.y, pa2 = p23.x, pa3 = p23.y;
    pa0 += __shfl_xor(pa0, 16, 64); pa0 += __shfl_xor(pa0, 32, 64);
    pa1 += __shfl_xor(pa1, 16, 64); pa1 += __shfl_xor(pa1, 32, 64);
    pa2 += __shfl_xor(pa2, 16, 64); pa2 += __shfl_xor(pa2, 32, 64);
    pa3 += __shfl_xor(pa3, 16, 64); pa3 += __shfl_xor(pa3, 32, 64);
    float outv = (q == 0) ? pa0 : (q == 1) ? pa1 : (q == 2) ? pa2 : pa3;
    aggr_b[(size_t)n * 64 + lane] = (unsigned short)bf16_bits(outv);
  }
}

// ---------- MFMA GRU, register-blocked B: wave w = dim chunk, all 4 gates ----------
__global__ __launch_bounds__(256) void k_gru_mfma(
    const unsigned short* __restrict__ aggr_b, const unsigned short* __restrict__ xb,
    const float* __restrict__ x, const unsigned short* __restrict__ Bt,
    const float* __restrict__ bih, const float* __restrict__ bhh,
    const float* __restrict__ root, const float* __restrict__ degf,
    float* __restrict__ h, float* __restrict__ bnsum, float* __restrict__ bnss) {
  int tid = threadIdx.x;
  int w = tid >> 6;
  int lane = tid & 63;
  int c = lane & 15, q = lane >> 4;
  int nbase = blockIdx.x * 128;
  int d = w * 16 + c;

  bf16x8 bfr[4][4];
#pragma unroll
  for (int g = 0; g < 4; g++)
#pragma unroll
    for (int kk = 0; kk < 4; kk++) {
      U4BF t;
      t.u = *(const uint4*)(Bt + (size_t)((g * 4 + w) * 16 + c) * 128 + kk * 32 + q * 8);
      bfr[g][kk] = t.v;
    }

  float br = bih[d] + bhh[d];
  float bz = bih[64 + d] + bhh[64 + d];
  float bin = bih[128 + d];
  float bhn = bhh[128 + d];
  float rt = root[d];
  float s1 = 0.f, s2 = 0.f;

#pragma unroll 2
  for (int mt = 0; mt < 8; mt++) {
    int na = nbase + mt * 16 + c;
    int nac = min(na, kN - 1);
    bf16x8 afr[4];
#pragma unroll
    for (int kk = 0; kk < 4; kk++) {
      const unsigned short* src = (kk < 2)
          ? aggr_b + (size_t)nac * 64 + kk * 32 + q * 8
          : xb + (size_t)nac * 64 + (kk - 2) * 32 + q * 8;
      U4BF t;
      t.u = *(const uint4*)src;
      afr[kk] = t.v;
    }
    f32x4 acc[4];
#pragma unroll
    for (int g = 0; g < 4; g++) {
      f32x4 a = {0.f, 0.f, 0.f, 0.f};
#pragma unroll
      for (int kk = 0; kk < 4; kk++)
        a = __builtin_amdgcn_mfma_f32_16x16x32_bf16(afr[kk], bfr[g][kk], a, 0, 0, 0);
      acc[g] = a;
    }
#pragma unroll
    for (int reg = 0; reg < 4; reg++) {
      int n = nbase + mt * 16 + q * 4 + reg;
      if (n < kN) {
        float xv = x[(size_t)n * 64 + d];
        float r = sigm(acc[0][reg] + br);
        float zz = sigm(acc[1][reg] + bz);
        float nn = tanh_f(acc[2][reg] + bin + r * (acc[3][reg] + bhn));
        float upd = (1.f - zz) * nn + zz * xv;
        float hl = upd + fmaxf(xv + rt, 0.f) / degf[n];
        h[(size_t)n * 64 + d] = hl;
        s1 += hl;
        s2 += hl * hl;
      }
    }
  }
  s1 += __shfl_xor(s1, 16, 64);
  s1 += __shfl_xor(s1, 32, 64);
  s2 += __shfl_xor(s2, 16, 64);
  s2 += __shfl_xor(s2, 32, 64);
  if (q == 0) {
    atomicAdd(&bnsum[d], s1);
    atomicAdd(&bnss[d], s2);
  }
}

// ---------- final BN (layer 2, no relu) -> d_out ----------
__global__ void k_final(const float* __restrict__ h, const float* __restrict__ bnsum,
                        const float* __restrict__ bnss, const float* __restrict__ bng,
                        const float* __restrict__ bnb, float* __restrict__ out) {
  int idx = blockIdx.x * blockDim.x + threadIdx.x;
  if (idx < kN * kD) {
    int d = idx & 63;
    float m = bnsum[d] * (1.f / (float)kN);
    float var = bnss[d] * (1.f / (float)kN) - m * m;
    float sc = rsqrtf(var + 1e-5f) * bng[d];
    out[idx] = (h[idx] - m) * sc + bnb[d];
  }
}

extern "C" void kernel_launch(void* const* d_in, const int* in_sizes, int n_in,
                              void* d_out, int out_size, void* d_ws, size_t ws_size,
                              hipStream_t stream) {
  const float* atom_x       = (const float*)d_in[0];
  const int*   atom_feature = (const int*)d_in[1];
  const int*   edge_index   = (const int*)d_in[2];
  const float* edge_attr    = (const float*)d_in[3];
  const float* atom_emb     = (const float*)d_in[4];
  const float* proj_W       = (const float*)d_in[5];
  const float* proj_b       = (const float*)d_in[6];
  const float* lin_W        = (const float*)d_in[7];
  const float* lin_b        = (const float*)d_in[8];
  const float* root_emb     = (const float*)d_in[9];
  const float* bond_W       = (const float*)d_in[10];
  const float* bond_b       = (const float*)d_in[11];
  const float* bond_g       = (const float*)d_in[12];
  const float* bond_beta    = (const float*)d_in[13];
  const float* gru_Wih      = (const float*)d_in[14];
  const float* gru_bih      = (const float*)d_in[15];
  const float* gru_Whh      = (const float*)d_in[16];
  const float* gru_bhh      = (const float*)d_in[17];
  const float* bn_g         = (const float*)d_in[18];
  const float* bn_b         = (const float*)d_in[19];
  float* out = (float*)d_out;

  const int* row = edge_index;
  const int* col = edge_index + kE;

  float* ws = (float*)d_ws;
  const size_t NH = (size_t)kN * kD;
  float* h     = ws;                         // NH
  float* x     = h + NH;                     // NH
  float* degf  = x + NH;                     // kN
  float* dinv  = degf + kN;                  // kN
  int*   cntr  = (int*)(dinv + kN);          // kN (reused: folded weights)
  int*   cntc  = cntr + kN;                  // kN (spare)
  int*   ptr   = cntc + kN;                  // kN+1 (reserve kN+4)
  int*   fill  = ptr + kN + 4;               // kN (spare)
  int*   loc   = fill + kN;                  // kN
  int*   bsum  = loc + kN;                   // 128
  int*   boff  = bsum + 128;                 // 128
  int2*  re    = (int2*)(boff + 128);        // kE int2
  float* nrm   = (float*)(re + kE);          // kE
  unsigned short* ea_s   = (unsigned short*)(nrm + kE);      // kE*16 + 1024 pad
  unsigned short* xb     = ea_s + (size_t)kE * 16 + 1024;    // N*64
  unsigned short* aggr_b = xb + (size_t)kN * 64;             // N*64
  unsigned short* Bt     = aggr_b + (size_t)kN * 64;         // 3*256*128
  unsigned short* WeffbT = Bt + 3 * 256 * 128;               // 3*64*16
  float* sumA  = (float*)(WeffbT + 3 * 64 * 16);  // 16
  float* Msum  = sumA + 16;                  // 256
  float* bnsum = Msum + 256;                 // 192 (3 layers x 64)
  float* bnss  = bnsum + 192;                // 192
  float* beff  = bnss + 192;                 // 192 (NOT zeroed; k_bnfold writes)

  // folded weights live in the (otherwise unused) cntr region
  unsigned short* WeffTb = (unsigned short*)cntr;          // 64*128 u16
  float* beff2 = (float*)(WeffTb + 64 * 128);              // 64 floats
  unsigned short* linWb  = (unsigned short*)(beff2 + 64);  // 3*64*64 u16

  // histogram partials live in the x region (12.8 MB; x dead until k_enc3)
  unsigned short* part = (unsigned short*)x;

  k_prep<<<440, 256, 0, stream>>>(proj_W, proj_b, lin_W, lin_b, gru_Wih, gru_Whh,
                                  WeffTb, beff2, linWb, Bt);
  // zero sumA+Msum+bnsum+bnss (656 floats) once, up-front
  hipMemsetAsync(sumA, 0, (16 + 256 + 192 + 192) * sizeof(float), stream);
  k_hist<<<kHC * kHS, 256, 0, stream>>>(row, col, part);
  k_scanA<<<kScanBlocks, 1024, 0, stream>>>(part, degf, dinv, loc, bsum);
  k_scanB<<<1, 128, 0, stream>>>(bsum, boff);
  k_scanC<<<kScanBlocks, 1024, 0, stream>>>(loc, boff, ptr);
  k_scatter2<<<kHC * kHS, 256, 0, stream>>>(row, col, dinv, ptr, part, re, nrm);
  // fused gea+stats (512 blocks, grid-stride)
  k_gea<<<512, 256, 0, stream>>>(re, edge_attr, ea_s, sumA, Msum);
  k_bnfold<<<1, 256, 0, stream>>>(sumA, Msum, bond_W, bond_b, bond_g, bond_beta,
                                  WeffbT, beff);
  k_enc3<<<kNB, 256, 0, stream>>>(atom_x, atom_feature, atom_emb, WeffTb, beff2,
                                  x, xb);

  for (int l = 0; l < 3; l++) {
    if (l > 0) {
      k_lin3<<<kNB, 256, 0, stream>>>(h, linWb + (size_t)l * 4096, lin_b + l * 64,
                                      bnsum + (l - 1) * 64, bnss + (l - 1) * 64,
                                      bn_g + (l - 1) * 64, bn_b + (l - 1) * 64,
                                      x, xb);
    }
    k_aggr<<<(kN + 15) / 16, 256, 0, stream>>>(ptr, re, nrm, ea_s, xb,
                                               WeffbT + (size_t)l * 64 * 16,
                                               beff + l * 64, aggr_b);
    k_gru_mfma<<<(kN + 127) / 128, 256, 0, stream>>>(
        aggr_b, xb, x, Bt + (size_t)l * 256 * 128, gru_bih + l * 192,
        gru_bhh + l * 192, root_emb + l * 64, degf, h,
        bnsum + l * 64, bnss + l * 64);
  }
  k_final<<<(kN * kD + 255) / 256, 256, 0, stream>>>(h, bnsum + 128, bnss + 128,
                                                     bn_g + 2 * 64, bn_b + 2 * 64,
                                                     out);
}

// Round 17
// 952.368 us; speedup vs baseline: 1.0752x; 1.0241x over previous
//
#include <hip/hip_runtime.h>
#include <hip/hip_bf16.h>

constexpr int kN    = 100000;
constexpr int kE    = 1600000;
constexpr int kD    = 64;
constexpr int kNF   = 9;
constexpr int kCARD = 16;
constexpr int kBF   = 16;
constexpr int kScanBlocks = (kN + 1023) / 1024;  // 98
constexpr int kNB   = (kN + 127) / 128;          // 782 node blocks

// histogram privatization geometry
constexpr int kHC    = 8;             // node chunks
constexpr int kHS    = 64;            // edge slices
constexpr int kChunk = kN / kHC;      // 12500 nodes per chunk
constexpr int kSlice = kE / kHS;      // 25000 edges per slice

typedef __bf16 bf16x8 __attribute__((ext_vector_type(8)));
typedef float f32x4 __attribute__((ext_vector_type(4)));
typedef float f32x2 __attribute__((ext_vector_type(2)));
union U4BF { uint4 u; bf16x8 v; };

__device__ __forceinline__ float sigm(float v) { return 1.f / (1.f + __expf(-v)); }
__device__ __forceinline__ float tanh_f(float v) { return 1.f - 2.f / (__expf(2.f * v) + 1.f); }

__device__ __forceinline__ unsigned bf16_bits(float v) {
  unsigned u = __float_as_uint(v);
  return (u + 0x7fffu + ((u >> 16) & 1u)) >> 16;
}

// ---------- privatized degree histogram: block (c,s) counts chunk c over slice s ----
__global__ __launch_bounds__(256) void k_hist(const int* __restrict__ row,
                                              const int* __restrict__ col,
                                              unsigned short* __restrict__ part) {
  __shared__ unsigned bins[kChunk];  // 50 KB
  int tid = threadIdx.x;
  int c = blockIdx.x / kHS, s = blockIdx.x % kHS;
  int nlo = c * kChunk;
  for (int i = tid; i < kChunk; i += 256) bins[i] = 0u;
  __syncthreads();
  int e0 = s * kSlice;
  for (int i = tid; i < kSlice; i += 256) {
    int r = row[e0 + i];
    int cc = col[e0 + i];
    unsigned ur = (unsigned)(r - nlo);
    unsigned uc = (unsigned)(cc - nlo);
    if (ur < (unsigned)kChunk) atomicAdd(&bins[ur], 1u);
    if (uc < (unsigned)kChunk) atomicAdd(&bins[uc], 0x10000u);
  }
  __syncthreads();
  unsigned short* dst = part + (size_t)blockIdx.x * kChunk;
  for (int i = tid; i < kChunk; i += 256) {
    unsigned v = bins[i];
    dst[i] = (unsigned short)((v & 0xffu) | ((v >> 8) & 0xff00u));
  }
}

// ---------- MERGED hmerge + scanA ----------
__global__ __launch_bounds__(1024) void k_scanA(
    unsigned short* __restrict__ part, float* __restrict__ degf,
    float* __restrict__ dinv, int* __restrict__ loc, int* __restrict__ bsum) {
  __shared__ int pl[1024];
  int tid = threadIdx.x;
  int n = blockIdx.x * 1024 + tid;
  int v = 0;
  if (n < kN) {
    int c = n / kChunk, j = n % kChunk;
    unsigned short* p = part + (size_t)c * kHS * kChunk + j;
    unsigned sr = 0, run = 0;
#pragma unroll
    for (int s = 0; s < kHS; s++) {
      unsigned vv = p[(size_t)s * kChunk];
      p[(size_t)s * kChunk] = (unsigned short)run;  // exclusive col prefix
      run += vv >> 8;
      sr += vv & 0xffu;
    }
    float d = (float)sr + 1.f;
    degf[n] = d;
    dinv[n] = rsqrtf(d);
    v = (int)run;
  }
  pl[tid] = v;
  __syncthreads();
  for (int off = 1; off < 1024; off <<= 1) {
    int t = (tid >= off) ? pl[tid - off] : 0;
    __syncthreads();
    pl[tid] += t;
    __syncthreads();
  }
  if (n < kN) loc[n] = pl[tid] - v;  // local exclusive
  if (tid == 1023) bsum[blockIdx.x] = pl[1023];
}

__global__ __launch_bounds__(128) void k_scanB(const int* __restrict__ bsum,
                                               int* __restrict__ boff) {
  __shared__ int p[128];
  int tid = threadIdx.x;
  int v = (tid < kScanBlocks) ? bsum[tid] : 0;
  p[tid] = v;
  __syncthreads();
  for (int off = 1; off < 128; off <<= 1) {
    int t = (tid >= off) ? p[tid - off] : 0;
    __syncthreads();
    p[tid] += t;
    __syncthreads();
  }
  boff[tid] = p[tid] - v;  // exclusive
}

__global__ __launch_bounds__(1024) void k_scanC(const int* __restrict__ loc,
                                                const int* __restrict__ boff,
                                                int* __restrict__ ptr) {
  int i = blockIdx.x * 1024 + threadIdx.x;
  if (i < kN) ptr[i] = loc[i] + boff[blockIdx.x];
  if (i == 0) ptr[kN] = kE;  // grand total is statically kE
}

// ---------- scatter via LDS offsets (zero global atomics) ----------
__global__ __launch_bounds__(256) void k_scatter2(
    const int* __restrict__ row, const int* __restrict__ col,
    const float* __restrict__ dinv, const int* __restrict__ ptr,
    const unsigned short* __restrict__ part,
    int2* __restrict__ re, float* __restrict__ nrm) {
  __shared__ unsigned bins[kChunk];  // 50 KB
  int tid = threadIdx.x;
  int c = blockIdx.x / kHS, s = blockIdx.x % kHS;
  int nlo = c * kChunk;
  const unsigned short* pp = part + (size_t)blockIdx.x * kChunk;
  for (int i = tid; i < kChunk; i += 256)
    bins[i] = (unsigned)ptr[nlo + i] + (unsigned)pp[i];
  __syncthreads();
  int e0 = s * kSlice;
  for (int i = tid; i < kSlice; i += 256) {
    int e = e0 + i;
    int cc = col[e];
    unsigned uc = (unsigned)(cc - nlo);
    if (uc < (unsigned)kChunk) {
      int r = row[e];
      int p = (int)atomicAdd(&bins[uc], 1u);
      re[p] = make_int2(r << 7, e);
      nrm[p] = dinv[r] * dinv[cc];
    }
  }
}

// ---------- MERGED gea + stats, SOFTWARE-PIPELINED ----------
// Prefetch group t+stride's gathered loads before the accumulate of group t,
// so the ~600ns gather hides under the 64-iter moment loop. 1024 blocks
// (4/CU) for wave-level interleave across the barriers.
__global__ __launch_bounds__(256) void k_gea(
    const int2* __restrict__ re, const float* __restrict__ ea,
    unsigned short* __restrict__ ea_s, float* __restrict__ sumA,
    float* __restrict__ Msum) {
  __shared__ float tile[1024];  // 64 edges x 16 dims
  int tid = threadIdx.x;
  int i = tid >> 4, j = tid & 15;
  int es = tid >> 2, cq = tid & 3;  // edge slot (0..63), quarter (0..3)
  float accM = 0.f, accS = 0.f;
  const int T = kE / 64;  // 25000 groups, exact
  int t = blockIdx.x;
  float4 v = {0.f, 0.f, 0.f, 0.f};
  int p = 0;
  if (t < T) {
    p = t * 64 + es;
    int e = re[p].y;
    v = *(const float4*)(ea + (size_t)e * 16 + cq * 4);
  }
  while (t < T) {
    ushort4 o;
    o.x = (unsigned short)bf16_bits(v.x);
    o.y = (unsigned short)bf16_bits(v.y);
    o.z = (unsigned short)bf16_bits(v.z);
    o.w = (unsigned short)bf16_bits(v.w);
    *(ushort4*)(ea_s + (size_t)p * 16 + cq * 4) = o;
    *(float4*)(tile + es * 16 + cq * 4) = v;
    __syncthreads();
    // prefetch next group's gather (latency hides under accumulate below)
    int tn = t + gridDim.x;
    float4 vn = {0.f, 0.f, 0.f, 0.f};
    int pn = p;
    if (tn < T) {
      pn = tn * 64 + es;
      int en = re[pn].y;
      vn = *(const float4*)(ea + (size_t)en * 16 + cq * 4);
    }
#pragma unroll 8
    for (int e2 = 0; e2 < 64; e2++) {
      float aj = tile[e2 * 16 + j];
      accM += tile[e2 * 16 + i] * aj;
      if (i == 0) accS += aj;
    }
    __syncthreads();
    v = vn;
    p = pn;
    t = tn;
  }
  atomicAdd(&Msum[i * 16 + j], accM);
  if (i == 0) atomicAdd(&sumA[j], accS);
}

// ---------- fold bond-linear + BN into WeffbT (bf16, [l][d][k]) + beff ----------
__global__ __launch_bounds__(256) void k_bnfold(
    const float* __restrict__ sumA, const float* __restrict__ Msum,
    const float* __restrict__ bond_W, const float* __restrict__ bond_b,
    const float* __restrict__ bond_g, const float* __restrict__ bond_beta,
    unsigned short* __restrict__ WeffbT, float* __restrict__ beff) {
  __shared__ float Ms[256];
  __shared__ float ab[16];
  int tid = threadIdx.x;
  Ms[tid] = Msum[tid] * (1.f / (float)kE);
  if (tid < 16) ab[tid] = sumA[tid] * (1.f / (float)kE);
  __syncthreads();
  if (tid < 192) {
    int l = tid / 64, d = tid % 64;
    const float* W = bond_W + l * kBF * kD;
    float w[16];
#pragma unroll
    for (int k = 0; k < 16; k++) w[k] = W[k * 64 + d];
    float b = bond_b[l * 64 + d];
    float lin = 0.f;
#pragma unroll
    for (int k = 0; k < 16; k++) lin += ab[k] * w[k];
    float mu = lin + b;
    float q = 0.f;
#pragma unroll
    for (int i = 0; i < 16; i++) {
      float wi = w[i];
#pragma unroll
      for (int k = 0; k < 16; k++) q += Ms[i * 16 + k] * wi * w[k];
    }
    float ex2 = q + 2.f * b * lin + b * b;
    float var = ex2 - mu * mu;
    float s = bond_g[l * 64 + d] * rsqrtf(var + 1e-6f);
#pragma unroll
    for (int k = 0; k < 16; k++)
      WeffbT[(size_t)(l * 64 + d) * 16 + k] = (unsigned short)bf16_bits(w[k] * s);
    beff[l * 64 + d] = (b - mu) * s + bond_beta[l * 64 + d];
  }
}

// ---------- MERGED weight prep: wfold (blocks 0-7) | wlin (8-55) | wprep (56-439) --
__global__ __launch_bounds__(256) void k_prep(
    const float* __restrict__ projW, const float* __restrict__ projb,
    const float* __restrict__ lin_W, const float* __restrict__ lin_b1,
    const float* __restrict__ Wih, const float* __restrict__ Whh,
    unsigned short* __restrict__ WeffTb, float* __restrict__ beff2,
    unsigned short* __restrict__ linWb, unsigned short* __restrict__ Bt) {
  __shared__ float W2[64 * 64];  // used by wfold branch only
  int tid = threadIdx.x;
  int bid = blockIdx.x;
  if (bid < 8) {
    for (int i = tid; i < 64 * 64 / 4; i += 256)
      ((float4*)W2)[i] = ((const float4*)lin_W)[i];  // lin_W[0] is first 64x64
    __syncthreads();
    int ccol = tid & 63, rg = tid >> 6;
#pragma unroll
    for (int i = 0; i < 4; i++) {
      int r = bid * 16 + rg + i * 4;
      float s = 0.f;
#pragma unroll 8
      for (int k = 0; k < 64; k++) s += projW[r * 64 + k] * W2[k * 64 + ccol];
      WeffTb[ccol * 128 + r] = (unsigned short)bf16_bits(s);
    }
    if (bid == 0 && tid < 64) {
      float s = lin_b1[tid];
      for (int k = 0; k < 64; k++) s += projb[k] * W2[k * 64 + tid];
      beff2[tid] = s;
    }
  } else if (bid < 56) {
    int idx = (bid - 8) * 256 + tid;
    int l = idx / 4096, rem = idx % 4096;
    int o = rem / 64, i = rem % 64;
    linWb[idx] = (unsigned short)bf16_bits(lin_W[l * 4096 + i * 64 + o]);
  } else {
    int idx = (bid - 56) * 256 + tid;  // 384*256 = 3*256*128 exact
    int l = idx / (256 * 128);
    int rem = idx % (256 * 128);
    int j = rem / 128, k = rem % 128;
    const float* ih = Wih + l * 192 * 64;
    const float* hh = Whh + l * 192 * 64;
    float v;
    if (k < 64) {
      if (j < 192) v = ih[j * 64 + k];
      else         v = 0.f;
    } else {
      int pos = k - 64;
      int kd = (pos & 3) * 16 + (pos >> 2);  // permuted x dim
      if (j < 128)      v = hh[j * 64 + kd];
      else if (j < 192) v = 0.f;
      else              v = hh[(j - 64) * 64 + kd];
    }
    Bt[idx] = (unsigned short)bf16_bits(v);
  }
}

// ---------- MFMA encoder: x = [atom_x | sum_f emb] @ Weff + beff2 ----------
__global__ __launch_bounds__(256) void k_enc3(
    const float* __restrict__ atom_x, const int* __restrict__ feat,
    const float* __restrict__ emb, const unsigned short* __restrict__ WTb,
    const float* __restrict__ beff2, float* __restrict__ xout,
    unsigned short* __restrict__ xb) {
  __shared__ unsigned short A[128 * 128];  // 32 KB
  int tid = threadIdx.x;
  int lane = tid & 63, wv = tid >> 6;
  int nbase = blockIdx.x * 128;
  for (int it = 0; it < 32; it++) {
    int nl = it * 4 + wv;
    int nc = min(nbase + nl, kN - 1);
    float ax = atom_x[(size_t)nc * 64 + lane];
    const int* fr = feat + (size_t)nc * kNF;
    float s = 0.f;
#pragma unroll
    for (int f = 0; f < kNF; f++) s += emb[(f * kCARD + fr[f]) * 64 + lane];
    int swz = (nl & 7) << 3;
    A[(nl * 128 + lane) ^ swz] = (unsigned short)bf16_bits(ax);
    A[(nl * 128 + 64 + lane) ^ swz] = (unsigned short)bf16_bits(s);
  }
  __syncthreads();
  int c = lane & 15, q = lane >> 4;
  int d = wv * 16 + c;
  bf16x8 bfr[4];
#pragma unroll
  for (int kk = 0; kk < 4; kk++) {
    U4BF t;
    t.u = *(const uint4*)(WTb + (size_t)d * 128 + kk * 32 + q * 8);
    bfr[kk] = t.v;
  }
  float bd = beff2[d];
  int perm = c * 4 + wv;  // (d&15)*4 + (d>>4)
  int rswz = (c & 7) << 3;
#pragma unroll 2
  for (int mt = 0; mt < 8; mt++) {
    bf16x8 afr[4];
#pragma unroll
    for (int kk = 0; kk < 4; kk++) {
      U4BF t;
      t.u = *(const uint4*)(A + (((mt * 16 + c) * 128 + kk * 32 + q * 8) ^ rswz));
      afr[kk] = t.v;
    }
    f32x4 a = {bd, bd, bd, bd};
#pragma unroll
    for (int kk = 0; kk < 4; kk++)
      a = __builtin_amdgcn_mfma_f32_16x16x32_bf16(afr[kk], bfr[kk], a, 0, 0, 0);
#pragma unroll
    for (int reg = 0; reg < 4; reg++) {
      int n = nbase + mt * 16 + q * 4 + reg;
      if (n < kN) {
        xout[(size_t)n * 64 + d] = a[reg];
        xb[(size_t)n * 64 + perm] = (unsigned short)bf16_bits(a[reg]);
      }
    }
  }
}

// ---------- MFMA lin (layers 1,2): x = relu(BN(h)) @ lin_W + lin_b ----------
__global__ __launch_bounds__(256) void k_lin3(
    const float* __restrict__ hin, const unsigned short* __restrict__ Wb,
    const float* __restrict__ bg,
    const float* __restrict__ bnsum, const float* __restrict__ bnss,
    const float* __restrict__ bng, const float* __restrict__ bnb,
    float* __restrict__ xout, unsigned short* __restrict__ xb) {
  __shared__ unsigned short A[128 * 64];  // 16 KB
  int tid = threadIdx.x;
  int lane = tid & 63, wv = tid >> 6;
  int nbase = blockIdx.x * 128;
  float m = bnsum[lane] * (1.f / (float)kN);
  float var = bnss[lane] * (1.f / (float)kN) - m * m;
  float sc = rsqrtf(var + 1e-5f) * bng[lane];
  float bb = bnb[lane];
  for (int it = 0; it < 32; it++) {
    int nl = it * 4 + wv;
    int nc = min(nbase + nl, kN - 1);
    float v = hin[(size_t)nc * 64 + lane];
    v = fmaxf((v - m) * sc + bb, 0.f);
    A[(nl * 64 + lane) ^ ((nl & 7) << 3)] = (unsigned short)bf16_bits(v);
  }
  __syncthreads();
  int c = lane & 15, q = lane >> 4;
  int d = wv * 16 + c;
  bf16x8 bfr[2];
#pragma unroll
  for (int kk = 0; kk < 2; kk++) {
    U4BF t;
    t.u = *(const uint4*)(Wb + (size_t)d * 64 + kk * 32 + q * 8);
    bfr[kk] = t.v;
  }
  float bd = bg[d];
  int perm = c * 4 + wv;
  int rswz = (c & 7) << 3;
#pragma unroll 2
  for (int mt = 0; mt < 8; mt++) {
    bf16x8 afr[2];
#pragma unroll
    for (int kk = 0; kk < 2; kk++) {
      U4BF t;
      t.u = *(const uint4*)(A + (((mt * 16 + c) * 64 + kk * 32 + q * 8) ^ rswz));
      afr[kk] = t.v;
    }
    f32x4 a = {bd, bd, bd, bd};
#pragma unroll
    for (int kk = 0; kk < 2; kk++)
      a = __builtin_amdgcn_mfma_f32_16x16x32_bf16(afr[kk], bfr[kk], a, 0, 0, 0);
#pragma unroll
    for (int reg = 0; reg < 4; reg++) {
      int n = nbase + mt * 16 + q * 4 + reg;
      if (n < kN) {
        xout[(size_t)n * 64 + d] = a[reg];
        xb[(size_t)n * 64 + perm] = (unsigned short)bf16_bits(a[reg]);
      }
    }
  }
}

// ---------- CSR gather with MFMA bond: 4 nodes per wave, prologue prefetch ----------
__global__ __launch_bounds__(256) void k_aggr(
    const int* __restrict__ ptr, const int2* __restrict__ re,
    const float* __restrict__ nrm, const unsigned short* __restrict__ ea_s,
    const unsigned short* __restrict__ xb, const unsigned short* __restrict__ WeffbT,
    const float* __restrict__ beff, unsigned short* __restrict__ aggr_b) {
  int lane = threadIdx.x & 63, wv = threadIdx.x >> 6;
  int nb = blockIdx.x * 16 + wv * 4;  // first of 4 nodes for this wave
  if (nb >= kN) return;
  int c = lane & 15, q = lane >> 4;

  U4BF z; z.u = make_uint4(0u, 0u, 0u, 0u);
  bf16x8 bfr[4];
#pragma unroll
  for (int nt = 0; nt < 4; nt++) {
    if (q < 2) {
      U4BF t;
      t.u = *(const uint4*)(WeffbT + (size_t)(nt * 16 + c) * 16 + q * 8);
      bfr[nt] = t.v;
    } else {
      bfr[nt] = z.v;
    }
  }
  float be4[4];
#pragma unroll
  for (int nt = 0; nt < 4; nt++) be4[nt] = beff[nt * 16 + c];
  const char* xcol = (const char*)xb + (c << 3);  // lane's 8B slice base
  const f32x2 zero2 = {0.f, 0.f};

  // prologue: ranges (uniform/scalar) + first-window re/nrm for all 4 nodes
  int st[4], en[4];
#pragma unroll
  for (int i = 0; i < 4; i++) {
    bool ok = (nb + i) < kN;
    st[i] = ok ? ptr[nb + i] : 0;
    en[i] = ok ? ptr[nb + i + 1] : 0;
  }
  int2 m0[4];
  float nr0[4];
#pragma unroll
  for (int i = 0; i < 4; i++) {
    int j = st[i] + lane;
    bool val = j < en[i];
    m0[i] = val ? re[j] : make_int2(0, 0);
    nr0[i] = val ? nrm[j] : 0.f;
  }

  for (int i = 0; i < 4; i++) {
    int n = nb + i;
    if (n >= kN) break;
    int start = st[i], end = en[i];
    f32x2 p01 = zero2, p23 = zero2;  // dims {c,16+c} and {32+c,48+c} partials
    int2 m = m0[i];
    float nr = nr0[i];

    for (int j0 = start; j0 < end; j0 += 64) {
      if (j0 != start) {  // windows >=1 (rare at avg degree 16)
        int j = j0 + lane;
        bool val = j < end;
        m = val ? re[j] : make_int2(0, 0);
        nr = val ? nrm[j] : 0.f;
      }
      int cnt = min(64, end - j0);
      int mts = (cnt + 15) >> 4;
      for (int mt = 0; mt < mts; mt++) {
        bf16x8 afr;
        if (q < 2) {
          U4BF t;
          t.u = *(const uint4*)(ea_s + (size_t)(j0 + mt * 16 + c) * 16 + q * 8);
          afr = t.v;
        } else {
          afr = z.v;
        }
        f32x4 bond[4];
#pragma unroll
        for (int nt = 0; nt < 4; nt++) {
          f32x4 a = {be4[nt], be4[nt], be4[nt], be4[nt]};
          bond[nt] = __builtin_amdgcn_mfma_f32_16x16x32_bf16(afr, bfr[nt], a, 0, 0, 0);
        }
#pragma unroll
        for (int reg = 0; reg < 4; reg++) {
          int el = mt * 16 + (q << 2) + reg;
          int rt = __builtin_amdgcn_ds_bpermute(el << 2, m.x);  // byte offset
          float nv = __uint_as_float(
              (unsigned)__builtin_amdgcn_ds_bpermute(el << 2, (int)__float_as_uint(nr)));
          uint2 xw = *(const uint2*)(xcol + rt);
          f32x2 xva = {__uint_as_float(xw.x << 16),
                       __uint_as_float(xw.x & 0xffff0000u)};
          f32x2 xvb = {__uint_as_float(xw.y << 16),
                       __uint_as_float(xw.y & 0xffff0000u)};
          f32x2 ba = {bond[0][reg], bond[1][reg]};
          f32x2 bb = {bond[2][reg], bond[3][reg]};
          f32x2 ta = __builtin_elementwise_max(xva + ba, zero2);
          f32x2 tb = __builtin_elementwise_max(xvb + bb, zero2);
          f32x2 nv2 = {nv, nv};
          p01 += nv2 * ta;
          p23 += nv2 * tb;
        }
      }
    }
    // reduce partials across quads (lanes c, c+16, c+32, c+48 share dims)
    float pa0 = p01.x, pa1 = p01.y, pa2 = p23.x, pa3 = p23.y;
    pa0 += __shfl_xor(pa0, 16, 64); pa0 += __shfl_xor(pa0, 32, 64);
    pa1 += __shfl_xor(pa1, 16, 64); pa1 += __shfl_xor(pa1, 32, 64);
    pa2 += __shfl_xor(pa2, 16, 64); pa2 += __shfl_xor(pa2, 32, 64);
    pa3 += __shfl_xor(pa3, 16, 64); pa3 += __shfl_xor(pa3, 32, 64);
    float outv = (q == 0) ? pa0 : (q == 1) ? pa1 : (q == 2) ? pa2 : pa3;
    aggr_b[(size_t)n * 64 + lane] = (unsigned short)bf16_bits(outv);
  }
}

// ---------- MFMA GRU, register-blocked B: wave w = dim chunk, all 4 gates ----------
__global__ __launch_bounds__(256) void k_gru_mfma(
    const unsigned short* __restrict__ aggr_b, const unsigned short* __restrict__ xb,
    const float* __restrict__ x, const unsigned short* __restrict__ Bt,
    const float* __restrict__ bih, const float* __restrict__ bhh,
    const float* __restrict__ root, const float* __restrict__ degf,
    float* __restrict__ h, float* __restrict__ bnsum, float* __restrict__ bnss) {
  int tid = threadIdx.x;
  int w = tid >> 6;
  int lane = tid & 63;
  int c = lane & 15, q = lane >> 4;
  int nbase = blockIdx.x * 128;
  int d = w * 16 + c;

  bf16x8 bfr[4][4];
#pragma unroll
  for (int g = 0; g < 4; g++)
#pragma unroll
    for (int kk = 0; kk < 4; kk++) {
      U4BF t;
      t.u = *(const uint4*)(Bt + (size_t)((g * 4 + w) * 16 + c) * 128 + kk * 32 + q * 8);
      bfr[g][kk] = t.v;
    }

  float br = bih[d] + bhh[d];
  float bz = bih[64 + d] + bhh[64 + d];
  float bin = bih[128 + d];
  float bhn = bhh[128 + d];
  float rt = root[d];
  float s1 = 0.f, s2 = 0.f;

#pragma unroll 2
  for (int mt = 0; mt < 8; mt++) {
    int na = nbase + mt * 16 + c;
    int nac = min(na, kN - 1);
    bf16x8 afr[4];
#pragma unroll
    for (int kk = 0; kk < 4; kk++) {
      const unsigned short* src = (kk < 2)
          ? aggr_b + (size_t)nac * 64 + kk * 32 + q * 8
          : xb + (size_t)nac * 64 + (kk - 2) * 32 + q * 8;
      U4BF t;
      t.u = *(const uint4*)src;
      afr[kk] = t.v;
    }
    f32x4 acc[4];
#pragma unroll
    for (int g = 0; g < 4; g++) {
      f32x4 a = {0.f, 0.f, 0.f, 0.f};
#pragma unroll
      for (int kk = 0; kk < 4; kk++)
        a = __builtin_amdgcn_mfma_f32_16x16x32_bf16(afr[kk], bfr[g][kk], a, 0, 0, 0);
      acc[g] = a;
    }
#pragma unroll
    for (int reg = 0; reg < 4; reg++) {
      int n = nbase + mt * 16 + q * 4 + reg;
      if (n < kN) {
        float xv = x[(size_t)n * 64 + d];
        float r = sigm(acc[0][reg] + br);
        float zz = sigm(acc[1][reg] + bz);
        float nn = tanh_f(acc[2][reg] + bin + r * (acc[3][reg] + bhn));
        float upd = (1.f - zz) * nn + zz * xv;
        float hl = upd + fmaxf(xv + rt, 0.f) / degf[n];
        h[(size_t)n * 64 + d] = hl;
        s1 += hl;
        s2 += hl * hl;
      }
    }
  }
  s1 += __shfl_xor(s1, 16, 64);
  s1 += __shfl_xor(s1, 32, 64);
  s2 += __shfl_xor(s2, 16, 64);
  s2 += __shfl_xor(s2, 32, 64);
  if (q == 0) {
    atomicAdd(&bnsum[d], s1);
    atomicAdd(&bnss[d], s2);
  }
}

// ---------- final BN (layer 2, no relu) -> d_out ----------
__global__ void k_final(const float* __restrict__ h, const float* __restrict__ bnsum,
                        const float* __restrict__ bnss, const float* __restrict__ bng,
                        const float* __restrict__ bnb, float* __restrict__ out) {
  int idx = blockIdx.x * blockDim.x + threadIdx.x;
  if (idx < kN * kD) {
    int d = idx & 63;
    float m = bnsum[d] * (1.f / (float)kN);
    float var = bnss[d] * (1.f / (float)kN) - m * m;
    float sc = rsqrtf(var + 1e-5f) * bng[d];
    out[idx] = (h[idx] - m) * sc + bnb[d];
  }
}

extern "C" void kernel_launch(void* const* d_in, const int* in_sizes, int n_in,
                              void* d_out, int out_size, void* d_ws, size_t ws_size,
                              hipStream_t stream) {
  const float* atom_x       = (const float*)d_in[0];
  const int*   atom_feature = (const int*)d_in[1];
  const int*   edge_index   = (const int*)d_in[2];
  const float* edge_attr    = (const float*)d_in[3];
  const float* atom_emb     = (const float*)d_in[4];
  const float* proj_W       = (const float*)d_in[5];
  const float* proj_b       = (const float*)d_in[6];
  const float* lin_W        = (const float*)d_in[7];
  const float* lin_b        = (const float*)d_in[8];
  const float* root_emb     = (const float*)d_in[9];
  const float* bond_W       = (const float*)d_in[10];
  const float* bond_b       = (const float*)d_in[11];
  const float* bond_g       = (const float*)d_in[12];
  const float* bond_beta    = (const float*)d_in[13];
  const float* gru_Wih      = (const float*)d_in[14];
  const float* gru_bih      = (const float*)d_in[15];
  const float* gru_Whh      = (const float*)d_in[16];
  const float* gru_bhh      = (const float*)d_in[17];
  const float* bn_g         = (const float*)d_in[18];
  const float* bn_b         = (const float*)d_in[19];
  float* out = (float*)d_out;

  const int* row = edge_index;
  const int* col = edge_index + kE;

  float* ws = (float*)d_ws;
  const size_t NH = (size_t)kN * kD;
  float* h     = ws;                         // NH
  float* x     = h + NH;                     // NH
  float* degf  = x + NH;                     // kN
  float* dinv  = degf + kN;                  // kN
  int*   cntr  = (int*)(dinv + kN);          // kN (reused: folded weights)
  int*   cntc  = cntr + kN;                  // kN (spare)
  int*   ptr   = cntc + kN;                  // kN+1 (reserve kN+4)
  int*   fill  = ptr + kN + 4;               // kN (spare)
  int*   loc   = fill + kN;                  // kN
  int*   bsum  = loc + kN;                   // 128
  int*   boff  = bsum + 128;                 // 128
  int2*  re    = (int2*)(boff + 128);        // kE int2
  float* nrm   = (float*)(re + kE);          // kE
  unsigned short* ea_s   = (unsigned short*)(nrm + kE);      // kE*16 + 1024 pad
  unsigned short* xb     = ea_s + (size_t)kE * 16 + 1024;    // N*64
  unsigned short* aggr_b = xb + (size_t)kN * 64;             // N*64
  unsigned short* Bt     = aggr_b + (size_t)kN * 64;         // 3*256*128
  unsigned short* WeffbT = Bt + 3 * 256 * 128;               // 3*64*16
  float* sumA  = (float*)(WeffbT + 3 * 64 * 16);  // 16
  float* Msum  = sumA + 16;                  // 256
  float* bnsum = Msum + 256;                 // 192 (3 layers x 64)
  float* bnss  = bnsum + 192;                // 192
  float* beff  = bnss + 192;                 // 192 (NOT zeroed; k_bnfold writes)

  // folded weights live in the (otherwise unused) cntr region
  unsigned short* WeffTb = (unsigned short*)cntr;          // 64*128 u16
  float* beff2 = (float*)(WeffTb + 64 * 128);              // 64 floats
  unsigned short* linWb  = (unsigned short*)(beff2 + 64);  // 3*64*64 u16

  // histogram partials live in the x region (12.8 MB; x dead until k_enc3)
  unsigned short* part = (unsigned short*)x;

  k_prep<<<440, 256, 0, stream>>>(proj_W, proj_b, lin_W, lin_b, gru_Wih, gru_Whh,
                                  WeffTb, beff2, linWb, Bt);
  // zero sumA+Msum+bnsum+bnss (656 floats) once, up-front
  hipMemsetAsync(sumA, 0, (16 + 256 + 192 + 192) * sizeof(float), stream);
  k_hist<<<kHC * kHS, 256, 0, stream>>>(row, col, part);
  k_scanA<<<kScanBlocks, 1024, 0, stream>>>(part, degf, dinv, loc, bsum);
  k_scanB<<<1, 128, 0, stream>>>(bsum, boff);
  k_scanC<<<kScanBlocks, 1024, 0, stream>>>(loc, boff, ptr);
  k_scatter2<<<kHC * kHS, 256, 0, stream>>>(row, col, dinv, ptr, part, re, nrm);
  // fused gea+stats: 1024 blocks (4/CU) + software-pipelined gather
  k_gea<<<1024, 256, 0, stream>>>(re, edge_attr, ea_s, sumA, Msum);
  k_bnfold<<<1, 256, 0, stream>>>(sumA, Msum, bond_W, bond_b, bond_g, bond_beta,
                                  WeffbT, beff);
  k_enc3<<<kNB, 256, 0, stream>>>(atom_x, atom_feature, atom_emb, WeffTb, beff2,
                                  x, xb);

  for (int l = 0; l < 3; l++) {
    if (l > 0) {
      k_lin3<<<kNB, 256, 0, stream>>>(h, linWb + (size_t)l * 4096, lin_b + l * 64,
                                      bnsum + (l - 1) * 64, bnss + (l - 1) * 64,
                                      bn_g + (l - 1) * 64, bn_b + (l - 1) * 64,
                                      x, xb);
    }
    k_aggr<<<(kN + 15) / 16, 256, 0, stream>>>(ptr, re, nrm, ea_s, xb,
                                               WeffbT + (size_t)l * 64 * 16,
                                               beff + l * 64, aggr_b);
    k_gru_mfma<<<(kN + 127) / 128, 256, 0, stream>>>(
        aggr_b, xb, x, Bt + (size_t)l * 256 * 128, gru_bih + l * 192,
        gru_bhh + l * 192, root_emb + l * 64, degf, h,
        bnsum + l * 64, bnss + l * 64);
  }
  k_final<<<(kN * kD + 255) / 256, 256, 0, stream>>>(h, bnsum + 128, bnss + 128,
                                                     bn_g + 2 * 64, bn_b + 2 * 64,
                                                     out);
}